// Round 6
// baseline (739.175 us; speedup 1.0000x reference)
//
#include <hip/hip_runtime.h>
#include <hip/hip_bf16.h>
#include <cstdint>

// Problem constants
#define T_SEQ  4096
#define DMODEL 512
#define DINNER 1024
#define MTOT   32768            // B*T = 8*4096 rows

typedef __bf16 bf16_t;
typedef bf16_t bf16x8 __attribute__((ext_vector_type(8)));
typedef bf16_t bf16x4v __attribute__((ext_vector_type(4)));
typedef float  f32x4  __attribute__((ext_vector_type(4)));

__device__ __forceinline__ void async_copy16(const bf16_t* g, bf16_t* l) {
  __builtin_amdgcn_global_load_lds(
      (const __attribute__((address_space(1))) void*)g,
      (__attribute__((address_space(3))) void*)l,
      16, 0, 0);
}

__device__ __forceinline__ float silu_f(float v) {
  return v / (1.f + __expf(-v));
}

// T1: bijective XCD-aware block swizzle (m204 form).
__device__ __forceinline__ int xcd_swizzle_flat() {
  const int nwg = gridDim.x * gridDim.y;
  const int orig = blockIdx.y * gridDim.x + blockIdx.x;
  const int q = nwg >> 3, r = nwg & 7;
  const int xcd = orig & 7, lid = orig >> 3;
  return (xcd < r ? xcd * (q + 1) : r * (q + 1) + (xcd - r) * q) + lid;
}

// fp32 -> bf16 cast, 4 elements/thread
__global__ __launch_bounds__(256) void cast_kernel(
    const float* __restrict__ s, bf16_t* __restrict__ d, int n4)
{
  const int i = blockIdx.x * 256 + threadIdx.x;
  if (i < n4) {
    const f32x4 v = ((const f32x4*)s)[i];
    bf16x4v o;
    o[0] = (bf16_t)v[0]; o[1] = (bf16_t)v[1];
    o[2] = (bf16_t)v[2]; o[3] = (bf16_t)v[3];
    ((bf16x4v*)d)[i] = o;
  }
}

// Transpose conv weight (DINNER,1,7) [c][k] -> wt[k][c] (7 x 1024 f32)
__global__ __launch_bounds__(256) void wtr_kernel(
    const float* __restrict__ w, float* __restrict__ wt)
{
  const int i = blockIdx.x * 256 + threadIdx.x;   // 7*1024 = 7168
  if (i < 7 * DINNER) {
    const int c = i & (DINNER - 1);
    const int k = i >> 10;
    wt[i] = w[c * 7 + k];
  }
}

// MFMA GEMM — m97 2-barrier drain K-loop (verified fast; source-level
// double-buffering regressed 2x in R3 — do not re-introduce without
// inline-asm waits). __launch_bounds__(256,2) is the BENCHED-GOOD setting;
// (256,3) coincided with a ~2x slowdown of the K=1024 GEMMs in R4/R5
// (suspect: scheduler occupancy-target change). Single-variable A/B here.
// + T1 XCD swizzle. C[m,n] = sum_k A[m,k]*B[n,k]
// A: MxK row-major bf16, B: NxK row-major bf16.
// EPI 0: plain bf16 store
// EPI 1: +bias(f32), silu, bf16 store                          (s_fwd)
// EPI 2: +resid(f32), f32 store                                (h)
// EPI 3: sb=silu(acc+bias); gate with sf/xzc/diag/gs, bf16 g   (s_bwd+gate)
template <int EPI>
__global__ __launch_bounds__(256, 2) void gemm_bt(
    const bf16_t* __restrict__ A, const bf16_t* __restrict__ B,
    bf16_t* __restrict__ Cb, float* __restrict__ Cf,
    const float* __restrict__ bias, const float* __restrict__ resid,
    const bf16_t* __restrict__ sf, const bf16_t* __restrict__ xzc,
    const float* __restrict__ diag, const float* __restrict__ gs,
    int r0, int loc0, int N, int K)
{
  constexpr int BM = 128, BN = 128, BK = 64;
  __shared__ __attribute__((aligned(16))) bf16_t sA[BM * BK];
  __shared__ __attribute__((aligned(16))) bf16_t sB[BN * BK];

  const int tid  = threadIdx.x;
  const int bflat = xcd_swizzle_flat();
  const int m0 = (bflat / gridDim.x) * BM;
  const int n0 = (bflat % gridDim.x) * BN;

  const int w    = tid >> 6, lane = tid & 63;
  const int wm   = (w & 1) << 6, wn = (w >> 1) << 6;   // 2x2 waves -> 64x64 each
  const int quad = lane >> 4, lrow = lane & 15;

  f32x4 acc[4][4] = {};

  for (int kt = 0; kt < K; kt += BK) {
    __syncthreads();   // protect LDS while prior tile in use
#pragma unroll
    for (int i = 0; i < 4; ++i) {
      const int f = (i * 256 + tid) << 3;    // flat bf16 index in 128x64 tile
      const int r = f >> 6, c = f & 63;
      async_copy16(&A[(size_t)(m0 + r) * K + kt + c], &sA[f]);
      async_copy16(&B[(size_t)(n0 + r) * K + kt + c], &sB[f]);
    }
    __syncthreads();   // vmcnt(0) drain happens here
#pragma unroll
    for (int ks = 0; ks < 2; ++ks) {
      const int ko = ks * 32 + (quad << 3);
      bf16x8 av[4], bv[4];
#pragma unroll
      for (int i = 0; i < 4; ++i) {
        av[i] = *(const bf16x8*)&sA[(wm + i * 16 + lrow) * BK + ko];
        bv[i] = *(const bf16x8*)&sB[(wn + i * 16 + lrow) * BK + ko];
      }
#pragma unroll
      for (int mi = 0; mi < 4; ++mi)
#pragma unroll
        for (int ni = 0; ni < 4; ++ni)
          acc[mi][ni] = __builtin_amdgcn_mfma_f32_16x16x32_bf16(
              av[mi], bv[ni], acc[mi][ni], 0, 0, 0);
    }
  }

  // C/D layout: col = lane&15, row = quad*4 + reg   [m89/m91 verified]
  float b1v[4], dgv[4];
  if constexpr (EPI == 1 || EPI == 3) {
#pragma unroll
    for (int ni = 0; ni < 4; ++ni) b1v[ni] = bias[n0 + wn + ni * 16 + lrow];
  }
  if constexpr (EPI == 3) {
#pragma unroll
    for (int ni = 0; ni < 4; ++ni) dgv[ni] = diag[n0 + wn + ni * 16 + lrow];
  }
  const float gsv = (EPI == 3) ? gs[0] : 0.f;

#pragma unroll
  for (int mi = 0; mi < 4; ++mi)
#pragma unroll
    for (int r = 0; r < 4; ++r) {
      const int row = m0 + wm + mi * 16 + (quad << 2) + r;
      if constexpr (EPI == 3) {
        const int t = (row + r0) & (T_SEQ - 1);
        const bool tf = (t > 0), tb = (t < T_SEQ - 1);
        const bf16_t* xrow = &xzc[(size_t)(loc0 + row) * 2048];
#pragma unroll
        for (int ni = 0; ni < 4; ++ni) {
          const int col = n0 + wn + ni * 16 + lrow;
          const float sb = silu_f(acc[mi][ni][r] + b1v[ni]);
          const float xp = (float)xrow[col];
          const float z  = (float)xrow[col + DINNER];
          float y = xp * dgv[ni];
          if (tf) y += (float)sf[(size_t)row * N + col];
          if (tb) y += sb;
          Cb[(size_t)row * N + col] = (bf16_t)(y * silu_f(z) * gsv);
        }
      } else {
#pragma unroll
        for (int ni = 0; ni < 4; ++ni) {
          const int col = n0 + wn + ni * 16 + lrow;
          float v = acc[mi][ni][r];
          if constexpr (EPI == 0) {
            Cb[(size_t)row * N + col] = (bf16_t)v;
          } else if constexpr (EPI == 1) {
            Cb[(size_t)row * N + col] = (bf16_t)silu_f(v + b1v[ni]);
          } else {
            v += resid[(size_t)row * N + col];
            Cf[(size_t)row * N + col] = v;
          }
        }
      }
    }
}

// Depthwise causal conv, one direction, shift_right folded in.
// Register-blocked + vectorized: each thread = 4 consecutive t x 8 channels.
template <int DIR>
__global__ __launch_bounds__(256) void conv_kernel(
    const bf16_t* __restrict__ xzc,
    const float* __restrict__ wt, const float* __restrict__ bc,
    bf16_t* __restrict__ vout, int r0, int loc0, int Mc)
{
  const int idx = blockIdx.x * 256 + threadIdx.x;   // over CH*DINNER/32
  const int c8  = idx & 127;                        // 8-channel group
  const int tg  = idx >> 7;                         // 4-row time group
  const int bt0 = tg << 2;                          // chunk-local first row
  const int t0  = (bt0 + r0) & (T_SEQ - 1);         // in-sequence t of first row
  const int lt0 = bt0 + loc0;                       // local row in xzc
  const int cc  = c8 << 3;

  float wv[7][8];
#pragma unroll
  for (int k = 0; k < 7; ++k) {
    const f32x4 a = *(const f32x4*)&wt[k * DINNER + cc];
    const f32x4 b = *(const f32x4*)&wt[k * DINNER + cc + 4];
#pragma unroll
    for (int u = 0; u < 4; ++u) { wv[k][u] = a[u]; wv[k][u + 4] = b[u]; }
  }

  float acc[4][8];
  {
    const f32x4 a = *(const f32x4*)&bc[cc];
    const f32x4 b = *(const f32x4*)&bc[cc + 4];
#pragma unroll
    for (int i = 0; i < 4; ++i)
#pragma unroll
      for (int u = 0; u < 4; ++u) { acc[i][u] = a[u]; acc[i][u + 4] = b[u]; }
  }

#pragma unroll
  for (int rr = 0; rr < 10; ++rr) {
    int lt = (DIR == 0) ? (lt0 - 7 + rr) : (lt0 + 1 + rr);
    lt = lt < 0 ? 0 : (lt > Mc - 1 ? Mc - 1 : lt);
    const bf16x8 xv = *(const bf16x8*)&xzc[(size_t)lt * 2048 + cc];
    float xf[8];
#pragma unroll
    for (int u = 0; u < 8; ++u) xf[u] = (float)xv[u];
#pragma unroll
    for (int i = 0; i < 4; ++i) {
      const int k = (DIR == 0) ? (rr - i) : (i + 6 - rr);
      if (k >= 0 && k <= 6) {
        const bool ok = (DIR == 0) ? (t0 + i >= 7 - k)
                                   : (t0 + i <= (T_SEQ - 8) + k);
        if (ok) {
#pragma unroll
          for (int u = 0; u < 8; ++u) acc[i][u] += wv[k][u] * xf[u];
        }
      }
    }
  }

#pragma unroll
  for (int i = 0; i < 4; ++i) {
    bf16x8 o;
#pragma unroll
    for (int u = 0; u < 8; ++u) o[u] = (bf16_t)acc[i][u];
    *(bf16x8*)&vout[(size_t)(bt0 + i) * DINNER + cc] = o;
  }
}

// LayerNorm over D=512, one block (256 threads) per chunk-local row.
__global__ __launch_bounds__(256) void ln_kernel(
    const float* __restrict__ h,
    const float* __restrict__ lng, const float* __restrict__ lnb,
    float* __restrict__ out, int r0)
{
  const int row = blockIdx.x;                        // local row
  const int tid = threadIdx.x;
  const float* hr = h + (size_t)row * DMODEL;
  const float v0 = hr[tid], v1 = hr[tid + 256];
  float s  = v0 + v1;
  float ss = v0 * v0 + v1 * v1;
#pragma unroll
  for (int off = 1; off < 64; off <<= 1) {
    s  += __shfl_xor(s, off);
    ss += __shfl_xor(ss, off);
  }
  __shared__ float ps[8];
  const int w = tid >> 6;
  if ((tid & 63) == 0) { ps[w] = s; ps[w + 4] = ss; }
  __syncthreads();
  s  = ps[0] + ps[1] + ps[2] + ps[3];
  ss = ps[4] + ps[5] + ps[6] + ps[7];
  const float mu  = s * (1.f / DMODEL);
  const float inv = rsqrtf(ss * (1.f / DMODEL) - mu * mu + 1e-5f);
  float* o = out + (size_t)(r0 + row) * DMODEL;
  o[tid]       = (v0 - mu) * inv * lng[tid]       + lnb[tid];
  o[tid + 256] = (v1 - mu) * inv * lng[tid + 256] + lnb[tid + 256];
}

extern "C" void kernel_launch(void* const* d_in, const int* in_sizes, int n_in,
                              void* d_out, int out_size, void* d_ws, size_t ws_size,
                              hipStream_t stream) {
  const float* x    = (const float*)d_in[0];
  const float* in_w = (const float*)d_in[1];
  const float* cfw  = (const float*)d_in[2];
  const float* cfb  = (const float*)d_in[3];
  const float* pfw  = (const float*)d_in[4];
  const float* pfb  = (const float*)d_in[5];
  const float* cbw  = (const float*)d_in[6];
  const float* cbb  = (const float*)d_in[7];
  const float* pbw  = (const float*)d_in[8];
  const float* pbb  = (const float*)d_in[9];
  const float* diag = (const float*)d_in[10];
  const float* gs   = (const float*)d_in[11];
  const float* ow   = (const float*)d_in[12];
  const float* lng  = (const float*)d_in[13];
  const float* lnb  = (const float*)d_in[14];
  float* out = (float*)d_out;

  char* ws = (char*)d_ws;

  // Persistent bf16 copies of GEMM operand tensors + transposed conv weights:
  bf16_t* xw   = (bf16_t*)(ws);                         // 32768x512   (32 MiB)
  bf16_t* inwb = (bf16_t*)(ws + (size_t)33554432);      // 2048x512    (2 MiB)
  bf16_t* pfwb = (bf16_t*)(ws + (size_t)35651584);      // 1024x1024   (2 MiB)
  bf16_t* pbwb = (bf16_t*)(ws + (size_t)37748736);      // 1024x1024   (2 MiB)
  bf16_t* owb  = (bf16_t*)(ws + (size_t)39845888);      // 512x1024    (1 MiB)
  float*  wtf  = (float*)(ws + (size_t)40894464);       // 7x1024 f32  (28 KiB)
  float*  wtb  = (float*)(ws + (size_t)40923136);       // 7x1024 f32  (28 KiB)
  const size_t persist = 40951808;

  // Workspace-adaptive chunking. CH=32768 = single chunk (no halo waste,
  // half the launch gaps); falls back if ws too small.
  // req(CH) = persist + (CH+256)*4096 + 3*CH*2048 bytes
  int CH = 128;
  {
    const int cands[9] = {32768, 16384, 8192, 4096, 2048, 1024, 512, 256, 128};
    for (int i = 0; i < 9; ++i) {
      const size_t req = persist + (size_t)(cands[i] + 256) * 4096 +
                         (size_t)3 * cands[i] * 2048;
      if (ws_size >= req) { CH = cands[i]; break; }
    }
  }

  char* cb = ws + persist;
  const size_t xz_cap = (size_t)(CH + 256) * 4096;      // bytes
  bf16_t* xzc  = (bf16_t*)cb;
  bf16_t* bufA = (bf16_t*)(cb + xz_cap);                      // v_fwd, later g
  bf16_t* bufB = (bf16_t*)(cb + xz_cap + (size_t)CH * 2048);  // v_bwd
  bf16_t* bufC = (bf16_t*)(cb + xz_cap + (size_t)CH * 4096);  // s_fwd
  float*  hbuf = (float*)cb;                             // aliases xzc (dead by then)

  dim3 blk(256);

  // 0) one-time fp32 -> bf16 casts of GEMM operands + conv-weight transposes
  cast_kernel<<<dim3(16384), blk, 0, stream>>>(x,    xw,   4194304);
  cast_kernel<<<dim3(1024),  blk, 0, stream>>>(in_w, inwb, 262144);
  cast_kernel<<<dim3(1024),  blk, 0, stream>>>(pfw,  pfwb, 262144);
  cast_kernel<<<dim3(1024),  blk, 0, stream>>>(pbw,  pbwb, 262144);
  cast_kernel<<<dim3(512),   blk, 0, stream>>>(ow,   owb,  131072);
  wtr_kernel<<<dim3(28), blk, 0, stream>>>(cfw, wtf);
  wtr_kernel<<<dim3(28), blk, 0, stream>>>(cbw, wtb);

  for (int r0 = 0; r0 < MTOT; r0 += CH) {
    const int g0 = (r0 >= 128) ? (r0 - 128) : 0;
    int g1 = r0 + CH + 128; if (g1 > MTOT) g1 = MTOT;
    const int Mc   = g1 - g0;        // multiple of 128
    const int loc0 = r0 - g0;        // chunk start's local row in xzc

    // 1) xzc = x[g0:g1] @ in_proj_w^T        (Mc x 2048, K=512)
    gemm_bt<0><<<dim3(2048 / 128, Mc / 128), blk, 0, stream>>>(
        xw + (size_t)g0 * 512, inwb, xzc, nullptr, nullptr, nullptr,
        nullptr, nullptr, nullptr, nullptr, 0, 0, 2048, 512);

    // 2) forward shifted causal conv -> v_fwd (bufA)
    conv_kernel<0><<<dim3(CH / 8), blk, 0, stream>>>(
        xzc, wtf, cfb, bufA, r0, loc0, Mc);

    // 3) backward shifted causal conv -> v_bwd (bufB)
    conv_kernel<1><<<dim3(CH / 8), blk, 0, stream>>>(
        xzc, wtb, cbb, bufB, r0, loc0, Mc);

    // 4) s_fwd = silu(v_fwd @ Pf^T + bf) -> bufC
    gemm_bt<1><<<dim3(1024 / 128, CH / 128), blk, 0, stream>>>(
        bufA, pfwb, bufC, nullptr, pfb, nullptr,
        nullptr, nullptr, nullptr, nullptr, 0, 0, 1024, 1024);

    // 5) sb GEMM + gate epilogue: g -> bufA (v_fwd dead)
    gemm_bt<3><<<dim3(1024 / 128, CH / 128), blk, 0, stream>>>(
        bufB, pbwb, bufA, nullptr, pbb, nullptr,
        bufC, xzc, diag, gs, r0, loc0, 1024, 1024);

    // 6) h = x + g @ out_proj^T (fp32) -> hbuf (aliases xzc; xz dead now)
    gemm_bt<2><<<dim3(512 / 128, CH / 128), blk, 0, stream>>>(
        bufA, owb, nullptr, hbuf, nullptr, x + (size_t)r0 * 512,
        nullptr, nullptr, nullptr, nullptr, 0, 0, 512, 1024);

    // 7) LayerNorm -> out rows [r0, r0+CH)   (fp32 store)
    ln_kernel<<<dim3(CH), blk, 0, stream>>>(hbuf, lng, lnb, out, r0);
  }
}

// Round 7
// 648.796 us; speedup vs baseline: 1.1393x; 1.1393x over previous
//
#include <hip/hip_runtime.h>
#include <hip/hip_bf16.h>
#include <cstdint>

// Problem constants
#define T_SEQ  4096
#define DMODEL 512
#define DINNER 1024
#define MTOT   32768            // B*T = 8*4096 rows

typedef __bf16 bf16_t;
typedef bf16_t bf16x8 __attribute__((ext_vector_type(8)));
typedef bf16_t bf16x4v __attribute__((ext_vector_type(4)));
typedef float  f32x4  __attribute__((ext_vector_type(4)));

__device__ __forceinline__ void async_copy16(const bf16_t* g, bf16_t* l) {
  __builtin_amdgcn_global_load_lds(
      (const __attribute__((address_space(1))) void*)g,
      (__attribute__((address_space(3))) void*)l,
      16, 0, 0);
}

__device__ __forceinline__ float silu_f(float v) {
  return v / (1.f + __expf(-v));
}

// T1: bijective XCD-aware block swizzle (m204 form).
__device__ __forceinline__ int xcd_swizzle_flat() {
  const int nwg = gridDim.x * gridDim.y;
  const int orig = blockIdx.y * gridDim.x + blockIdx.x;
  const int q = nwg >> 3, r = nwg & 7;
  const int xcd = orig & 7, lid = orig >> 3;
  return (xcd < r ? xcd * (q + 1) : r * (q + 1) + (xcd - r) * q) + lid;
}

// fp32 -> bf16 cast, 4 elements/thread
__global__ __launch_bounds__(256) void cast_kernel(
    const float* __restrict__ s, bf16_t* __restrict__ d, int n4)
{
  const int i = blockIdx.x * 256 + threadIdx.x;
  if (i < n4) {
    const f32x4 v = ((const f32x4*)s)[i];
    bf16x4v o;
    o[0] = (bf16_t)v[0]; o[1] = (bf16_t)v[1];
    o[2] = (bf16_t)v[2]; o[3] = (bf16_t)v[3];
    ((bf16x4v*)d)[i] = o;
  }
}

// Transpose conv weight (DINNER,1,7) [c][k] -> wt[k][c] (7 x 1024 f32)
__global__ __launch_bounds__(256) void wtr_kernel(
    const float* __restrict__ w, float* __restrict__ wt)
{
  const int i = blockIdx.x * 256 + threadIdx.x;   // 7*1024 = 7168
  if (i < 7 * DINNER) {
    const int c = i & (DINNER - 1);
    const int k = i >> 10;
    wt[i] = w[c * 7 + k];
  }
}

// MFMA GEMM (m97 2-barrier drain structure + T1 XCD swizzle).
// SESSION LESSONS (do not regress):
//  - Source-level double-buffered K-loop: 2x REGRESSION (R3/R4) — hipcc
//    serializes global_load_lds vs ds_read across LDS buffers. Only an
//    inline-asm counted-vmcnt schedule (8-phase template) may change this.
//  - launch_bounds (256,2) vs (256,3): measured identical (R6 A/B).
//  - Scatter-heavy epilogues (per-element 2B reads of other tensors, e.g.
//    the R4 EPI3 sf/xzc gate) cost ~50 us per K=1024 dispatch. Gate must
//    either be standalone-vectorized or fully in-register (gemm_dual).
// C[m,n] = sum_k A[m,k]*B[n,k]; A: MxK, B: NxK, both row-major bf16.
// EPI 0: plain bf16 store
// EPI 2: +resid(f32), f32 store
template <int EPI>
__global__ __launch_bounds__(256, 3) void gemm_bt(
    const bf16_t* __restrict__ A, const bf16_t* __restrict__ B,
    bf16_t* __restrict__ Cb, float* __restrict__ Cf,
    const float* __restrict__ resid,
    int N, int K)
{
  constexpr int BM = 128, BN = 128, BK = 64;
  __shared__ __attribute__((aligned(16))) bf16_t sA[BM * BK];
  __shared__ __attribute__((aligned(16))) bf16_t sB[BN * BK];

  const int tid  = threadIdx.x;
  const int bflat = xcd_swizzle_flat();
  const int m0 = (bflat / gridDim.x) * BM;
  const int n0 = (bflat % gridDim.x) * BN;

  const int w    = tid >> 6, lane = tid & 63;
  const int wm   = (w & 1) << 6, wn = (w >> 1) << 6;   // 2x2 waves -> 64x64 each
  const int quad = lane >> 4, lrow = lane & 15;

  f32x4 acc[4][4] = {};

  for (int kt = 0; kt < K; kt += BK) {
    __syncthreads();   // protect LDS while prior tile in use
#pragma unroll
    for (int i = 0; i < 4; ++i) {
      const int f = (i * 256 + tid) << 3;    // flat bf16 index in 128x64 tile
      const int r = f >> 6, c = f & 63;
      async_copy16(&A[(size_t)(m0 + r) * K + kt + c], &sA[f]);
      async_copy16(&B[(size_t)(n0 + r) * K + kt + c], &sB[f]);
    }
    __syncthreads();   // vmcnt(0) drain happens here
#pragma unroll
    for (int ks = 0; ks < 2; ++ks) {
      const int ko = ks * 32 + (quad << 3);
      bf16x8 av[4], bv[4];
#pragma unroll
      for (int i = 0; i < 4; ++i) {
        av[i] = *(const bf16x8*)&sA[(wm + i * 16 + lrow) * BK + ko];
        bv[i] = *(const bf16x8*)&sB[(wn + i * 16 + lrow) * BK + ko];
      }
#pragma unroll
      for (int mi = 0; mi < 4; ++mi)
#pragma unroll
        for (int ni = 0; ni < 4; ++ni)
          acc[mi][ni] = __builtin_amdgcn_mfma_f32_16x16x32_bf16(
              av[mi], bv[ni], acc[mi][ni], 0, 0, 0);
    }
  }

  // C/D layout: col = lane&15, row = quad*4 + reg   [m89/m91 verified]
#pragma unroll
  for (int mi = 0; mi < 4; ++mi)
#pragma unroll
    for (int ni = 0; ni < 4; ++ni)
#pragma unroll
      for (int r = 0; r < 4; ++r) {
        const int row = m0 + wm + mi * 16 + (quad << 2) + r;
        const int col = n0 + wn + ni * 16 + lrow;
        float v = acc[mi][ni][r];
        if constexpr (EPI == 0) {
          Cb[(size_t)row * N + col] = (bf16_t)v;
        } else {
          v += resid[(size_t)row * N + col];
          Cf[(size_t)row * N + col] = v;
        }
      }
}

// Fused dual GEMM + gate (steps 3+5+6) — the 647-us champion config:
//   sf = silu(A1 @ B1^T + b1)   (in registers, never touches HBM)
//   sb = silu(A2 @ B2^T + b2)   (in registers)
//   G  = (sf*[t>0] + sb*[t<T-1] + xp*diag) * silu(z) * gs
// A1 = v_fwd, A2 = v_bwd (M x K bf16), B1 = Pf, B2 = Pb (N x K bf16).
// Measured (R3 counters): ~170 us/chunk, MfmaUtil 16.6, FETCH 98.6 MB
// (= compulsory). Fat (64 KiB LDS, 128 acc regs) but beats any split that
// round-trips sf through HBM + scattered epilogue reads (R4-R6: +92 us).
__global__ __launch_bounds__(256, 2) void gemm_dual(
    const bf16_t* __restrict__ A1, const bf16_t* __restrict__ A2,
    const bf16_t* __restrict__ B1, const bf16_t* __restrict__ B2,
    const float* __restrict__ b1, const float* __restrict__ b2,
    const bf16_t* __restrict__ xzc, const float* __restrict__ diag,
    const float* __restrict__ gs, bf16_t* __restrict__ G,
    int r0, int loc0, int N, int K)
{
  constexpr int BM = 128, BN = 128, BK = 64;
  __shared__ __attribute__((aligned(16))) bf16_t sA1[BM * BK];
  __shared__ __attribute__((aligned(16))) bf16_t sA2[BM * BK];
  __shared__ __attribute__((aligned(16))) bf16_t sB1[BN * BK];
  __shared__ __attribute__((aligned(16))) bf16_t sB2[BN * BK];

  const int tid  = threadIdx.x;
  const int bflat = xcd_swizzle_flat();
  const int m0 = (bflat / gridDim.x) * BM;
  const int n0 = (bflat % gridDim.x) * BN;

  const int w    = tid >> 6, lane = tid & 63;
  const int wm   = (w & 1) << 6, wn = (w >> 1) << 6;
  const int quad = lane >> 4, lrow = lane & 15;

  f32x4 accf[4][4] = {};
  f32x4 accb[4][4] = {};

  for (int kt = 0; kt < K; kt += BK) {
    __syncthreads();
#pragma unroll
    for (int i = 0; i < 4; ++i) {
      const int f = (i * 256 + tid) << 3;
      const int r = f >> 6, c = f & 63;
      const size_t ga = (size_t)(m0 + r) * K + kt + c;
      const size_t gb = (size_t)(n0 + r) * K + kt + c;
      async_copy16(&A1[ga], &sA1[f]);
      async_copy16(&A2[ga], &sA2[f]);
      async_copy16(&B1[gb], &sB1[f]);
      async_copy16(&B2[gb], &sB2[f]);
    }
    __syncthreads();
#pragma unroll
    for (int ks = 0; ks < 2; ++ks) {
      const int ko = ks * 32 + (quad << 3);
      bf16x8 av[4], bv[4];
#pragma unroll
      for (int i = 0; i < 4; ++i) {
        av[i] = *(const bf16x8*)&sA1[(wm + i * 16 + lrow) * BK + ko];
        bv[i] = *(const bf16x8*)&sB1[(wn + i * 16 + lrow) * BK + ko];
      }
#pragma unroll
      for (int mi = 0; mi < 4; ++mi)
#pragma unroll
        for (int ni = 0; ni < 4; ++ni)
          accf[mi][ni] = __builtin_amdgcn_mfma_f32_16x16x32_bf16(
              av[mi], bv[ni], accf[mi][ni], 0, 0, 0);
#pragma unroll
      for (int i = 0; i < 4; ++i) {
        av[i] = *(const bf16x8*)&sA2[(wm + i * 16 + lrow) * BK + ko];
        bv[i] = *(const bf16x8*)&sB2[(wn + i * 16 + lrow) * BK + ko];
      }
#pragma unroll
      for (int mi = 0; mi < 4; ++mi)
#pragma unroll
        for (int ni = 0; ni < 4; ++ni)
          accb[mi][ni] = __builtin_amdgcn_mfma_f32_16x16x32_bf16(
              av[mi], bv[ni], accb[mi][ni], 0, 0, 0);
    }
  }

  // Epilogue: per-element gate, all in registers.
  const float gsv = gs[0];
  int   colv[4];
  float b1v[4], b2v[4], dgv[4];
#pragma unroll
  for (int ni = 0; ni < 4; ++ni) {
    const int col = n0 + wn + ni * 16 + lrow;
    colv[ni] = col;
    b1v[ni] = b1[col];
    b2v[ni] = b2[col];
    dgv[ni] = diag[col];
  }
#pragma unroll
  for (int mi = 0; mi < 4; ++mi)
#pragma unroll
    for (int r = 0; r < 4; ++r) {
      const int row = m0 + wm + mi * 16 + (quad << 2) + r;
      const int t = (row + r0) & (T_SEQ - 1);
      const bool tf = (t > 0), tb = (t < T_SEQ - 1);
      const bf16_t* xrow = &xzc[(size_t)(loc0 + row) * 2048];
#pragma unroll
      for (int ni = 0; ni < 4; ++ni) {
        const float sf = silu_f(accf[mi][ni][r] + b1v[ni]);
        const float sb = silu_f(accb[mi][ni][r] + b2v[ni]);
        const float xp = (float)xrow[colv[ni]];
        const float z  = (float)xrow[colv[ni] + DINNER];
        float y = xp * dgv[ni];
        if (tf) y += sf;
        if (tb) y += sb;
        G[(size_t)row * N + colv[ni]] = (bf16_t)(y * silu_f(z) * gsv);
      }
    }
}

// Depthwise causal conv, one direction, shift_right folded in.
// Register-blocked + vectorized: each thread = 4 consecutive t x 8 channels.
template <int DIR>
__global__ __launch_bounds__(256) void conv_kernel(
    const bf16_t* __restrict__ xzc,
    const float* __restrict__ wt, const float* __restrict__ bc,
    bf16_t* __restrict__ vout, int r0, int loc0, int Mc)
{
  const int idx = blockIdx.x * 256 + threadIdx.x;   // over CH*DINNER/32
  const int c8  = idx & 127;                        // 8-channel group
  const int tg  = idx >> 7;                         // 4-row time group
  const int bt0 = tg << 2;                          // chunk-local first row
  const int t0  = (bt0 + r0) & (T_SEQ - 1);         // in-sequence t of first row
  const int lt0 = bt0 + loc0;                       // local row in xzc
  const int cc  = c8 << 3;

  float wv[7][8];
#pragma unroll
  for (int k = 0; k < 7; ++k) {
    const f32x4 a = *(const f32x4*)&wt[k * DINNER + cc];
    const f32x4 b = *(const f32x4*)&wt[k * DINNER + cc + 4];
#pragma unroll
    for (int u = 0; u < 4; ++u) { wv[k][u] = a[u]; wv[k][u + 4] = b[u]; }
  }

  float acc[4][8];
  {
    const f32x4 a = *(const f32x4*)&bc[cc];
    const f32x4 b = *(const f32x4*)&bc[cc + 4];
#pragma unroll
    for (int i = 0; i < 4; ++i)
#pragma unroll
      for (int u = 0; u < 4; ++u) { acc[i][u] = a[u]; acc[i][u + 4] = b[u]; }
  }

#pragma unroll
  for (int rr = 0; rr < 10; ++rr) {
    int lt = (DIR == 0) ? (lt0 - 7 + rr) : (lt0 + 1 + rr);
    lt = lt < 0 ? 0 : (lt > Mc - 1 ? Mc - 1 : lt);
    const bf16x8 xv = *(const bf16x8*)&xzc[(size_t)lt * 2048 + cc];
    float xf[8];
#pragma unroll
    for (int u = 0; u < 8; ++u) xf[u] = (float)xv[u];
#pragma unroll
    for (int i = 0; i < 4; ++i) {
      const int k = (DIR == 0) ? (rr - i) : (i + 6 - rr);
      if (k >= 0 && k <= 6) {
        const bool ok = (DIR == 0) ? (t0 + i >= 7 - k)
                                   : (t0 + i <= (T_SEQ - 8) + k);
        if (ok) {
#pragma unroll
          for (int u = 0; u < 8; ++u) acc[i][u] += wv[k][u] * xf[u];
        }
      }
    }
  }

#pragma unroll
  for (int i = 0; i < 4; ++i) {
    bf16x8 o;
#pragma unroll
    for (int u = 0; u < 8; ++u) o[u] = (bf16_t)acc[i][u];
    *(bf16x8*)&vout[(size_t)(bt0 + i) * DINNER + cc] = o;
  }
}

// LayerNorm over D=512, one block (256 threads) per chunk-local row.
__global__ __launch_bounds__(256) void ln_kernel(
    const float* __restrict__ h,
    const float* __restrict__ lng, const float* __restrict__ lnb,
    float* __restrict__ out, int r0)
{
  const int row = blockIdx.x;                        // local row
  const int tid = threadIdx.x;
  const float* hr = h + (size_t)row * DMODEL;
  const float v0 = hr[tid], v1 = hr[tid + 256];
  float s  = v0 + v1;
  float ss = v0 * v0 + v1 * v1;
#pragma unroll
  for (int off = 1; off < 64; off <<= 1) {
    s  += __shfl_xor(s, off);
    ss += __shfl_xor(ss, off);
  }
  __shared__ float ps[8];
  const int w = tid >> 6;
  if ((tid & 63) == 0) { ps[w] = s; ps[w + 4] = ss; }
  __syncthreads();
  s  = ps[0] + ps[1] + ps[2] + ps[3];
  ss = ps[4] + ps[5] + ps[6] + ps[7];
  const float mu  = s * (1.f / DMODEL);
  const float inv = rsqrtf(ss * (1.f / DMODEL) - mu * mu + 1e-5f);
  float* o = out + (size_t)(r0 + row) * DMODEL;
  o[tid]       = (v0 - mu) * inv * lng[tid]       + lnb[tid];
  o[tid + 256] = (v1 - mu) * inv * lng[tid + 256] + lnb[tid + 256];
}

extern "C" void kernel_launch(void* const* d_in, const int* in_sizes, int n_in,
                              void* d_out, int out_size, void* d_ws, size_t ws_size,
                              hipStream_t stream) {
  const float* x    = (const float*)d_in[0];
  const float* in_w = (const float*)d_in[1];
  const float* cfw  = (const float*)d_in[2];
  const float* cfb  = (const float*)d_in[3];
  const float* pfw  = (const float*)d_in[4];
  const float* pfb  = (const float*)d_in[5];
  const float* cbw  = (const float*)d_in[6];
  const float* cbb  = (const float*)d_in[7];
  const float* pbw  = (const float*)d_in[8];
  const float* pbb  = (const float*)d_in[9];
  const float* diag = (const float*)d_in[10];
  const float* gs   = (const float*)d_in[11];
  const float* ow   = (const float*)d_in[12];
  const float* lng  = (const float*)d_in[13];
  const float* lnb  = (const float*)d_in[14];
  float* out = (float*)d_out;

  char* ws = (char*)d_ws;

  // Persistent bf16 copies of GEMM operand tensors + transposed conv weights:
  bf16_t* xw   = (bf16_t*)(ws);                         // 32768x512   (32 MiB)
  bf16_t* inwb = (bf16_t*)(ws + (size_t)33554432);      // 2048x512    (2 MiB)
  bf16_t* pfwb = (bf16_t*)(ws + (size_t)35651584);      // 1024x1024   (2 MiB)
  bf16_t* pbwb = (bf16_t*)(ws + (size_t)37748736);      // 1024x1024   (2 MiB)
  bf16_t* owb  = (bf16_t*)(ws + (size_t)39845888);      // 512x1024    (1 MiB)
  float*  wtf  = (float*)(ws + (size_t)40894464);       // 7x1024 f32  (28 KiB)
  float*  wtb  = (float*)(ws + (size_t)40923136);       // 7x1024 f32  (28 KiB)
  const size_t persist = 40951808;

  // Workspace-adaptive chunking. (Observed on this harness: ws fits
  // CH=16384 but not 32768 -> 2 chunks; 32768 cand kept for bigger ws.)
  // req(CH) = persist + (CH+256)*4096 + 3*CH*2048 bytes
  int CH = 128;
  {
    const int cands[9] = {32768, 16384, 8192, 4096, 2048, 1024, 512, 256, 128};
    for (int i = 0; i < 9; ++i) {
      const size_t req = persist + (size_t)(cands[i] + 256) * 4096 +
                         (size_t)3 * cands[i] * 2048;
      if (ws_size >= req) { CH = cands[i]; break; }
    }
  }

  char* cb = ws + persist;
  const size_t xz_cap = (size_t)(CH + 256) * 4096;      // bytes
  bf16_t* xzc  = (bf16_t*)cb;
  bf16_t* bufA = (bf16_t*)(cb + xz_cap);                      // v_fwd
  bf16_t* bufB = (bf16_t*)(cb + xz_cap + (size_t)CH * 2048);  // v_bwd
  bf16_t* bufC = (bf16_t*)(cb + xz_cap + (size_t)CH * 4096);  // g
  float*  hbuf = (float*)cb;                             // aliases xzc (dead by then)

  dim3 blk(256);

  // 0) one-time fp32 -> bf16 casts of GEMM operands + conv-weight transposes
  cast_kernel<<<dim3(16384), blk, 0, stream>>>(x,    xw,   4194304);
  cast_kernel<<<dim3(1024),  blk, 0, stream>>>(in_w, inwb, 262144);
  cast_kernel<<<dim3(1024),  blk, 0, stream>>>(pfw,  pfwb, 262144);
  cast_kernel<<<dim3(1024),  blk, 0, stream>>>(pbw,  pbwb, 262144);
  cast_kernel<<<dim3(512),   blk, 0, stream>>>(ow,   owb,  131072);
  wtr_kernel<<<dim3(28), blk, 0, stream>>>(cfw, wtf);
  wtr_kernel<<<dim3(28), blk, 0, stream>>>(cbw, wtb);

  for (int r0 = 0; r0 < MTOT; r0 += CH) {
    const int g0 = (r0 >= 128) ? (r0 - 128) : 0;
    int g1 = r0 + CH + 128; if (g1 > MTOT) g1 = MTOT;
    const int Mc   = g1 - g0;        // multiple of 128
    const int loc0 = r0 - g0;        // chunk start's local row in xzc

    // 1) xzc = x[g0:g1] @ in_proj_w^T        (Mc x 2048, K=512)
    gemm_bt<0><<<dim3(2048 / 128, Mc / 128), blk, 0, stream>>>(
        xw + (size_t)g0 * 512, inwb, xzc, nullptr, nullptr, 2048, 512);

    // 2) forward shifted causal conv -> v_fwd (bufA)
    conv_kernel<0><<<dim3(CH / 8), blk, 0, stream>>>(
        xzc, wtf, cfb, bufA, r0, loc0, Mc);

    // 3) backward shifted causal conv -> v_bwd (bufB)
    conv_kernel<1><<<dim3(CH / 8), blk, 0, stream>>>(
        xzc, wtb, cbb, bufB, r0, loc0, Mc);

    // 4) fused: sf/sb GEMMs + gate -> g (bufC)
    gemm_dual<<<dim3(1024 / 128, CH / 128), blk, 0, stream>>>(
        bufA, bufB, pfwb, pbwb, pfb, pbb, xzc, diag, gs, bufC,
        r0, loc0, 1024, 1024);

    // 5) h = x + g @ out_proj^T (fp32) -> hbuf (aliases xzc; xz dead now)
    gemm_bt<2><<<dim3(512 / 128, CH / 128), blk, 0, stream>>>(
        bufC, owb, nullptr, hbuf, x + (size_t)r0 * 512, 512, 1024);

    // 6) LayerNorm -> out rows [r0, r0+CH)   (fp32 store)
    ln_kernel<<<dim3(CH), blk, 0, stream>>>(hbuf, lng, lnb, out, r0);
  }
}

// Round 8
// 641.757 us; speedup vs baseline: 1.1518x; 1.0110x over previous
//
#include <hip/hip_runtime.h>
#include <hip/hip_bf16.h>
#include <cstdint>

// Problem constants
#define T_SEQ  4096
#define DMODEL 512
#define DINNER 1024
#define MTOT   32768            // B*T = 8*4096 rows

typedef __bf16 bf16_t;
typedef bf16_t bf16x8 __attribute__((ext_vector_type(8)));
typedef bf16_t bf16x4v __attribute__((ext_vector_type(4)));
typedef float  f32x4  __attribute__((ext_vector_type(4)));

__device__ __forceinline__ void async_copy16(const bf16_t* g, bf16_t* l) {
  __builtin_amdgcn_global_load_lds(
      (const __attribute__((address_space(1))) void*)g,
      (__attribute__((address_space(3))) void*)l,
      16, 0, 0);
}

__device__ __forceinline__ float silu_f(float v) {
  return v / (1.f + __expf(-v));
}

// T1: bijective XCD-aware block swizzle (m204 form).
__device__ __forceinline__ int xcd_swizzle_flat() {
  const int nwg = gridDim.x * gridDim.y;
  const int orig = blockIdx.y * gridDim.x + blockIdx.x;
  const int q = nwg >> 3, r = nwg & 7;
  const int xcd = orig & 7, lid = orig >> 3;
  return (xcd < r ? xcd * (q + 1) : r * (q + 1) + (xcd - r) * q) + lid;
}

// fp32 -> bf16 cast, 4 elements/thread
__global__ __launch_bounds__(256) void cast_kernel(
    const float* __restrict__ s, bf16_t* __restrict__ d, int n4)
{
  const int i = blockIdx.x * 256 + threadIdx.x;
  if (i < n4) {
    const f32x4 v = ((const f32x4*)s)[i];
    bf16x4v o;
    o[0] = (bf16_t)v[0]; o[1] = (bf16_t)v[1];
    o[2] = (bf16_t)v[2]; o[3] = (bf16_t)v[3];
    ((bf16x4v*)d)[i] = o;
  }
}

// Transpose conv weight (DINNER,1,7) [c][k] -> wt[k][c] (7 x 1024 f32)
__global__ __launch_bounds__(256) void wtr_kernel(
    const float* __restrict__ w, float* __restrict__ wt)
{
  const int i = blockIdx.x * 256 + threadIdx.x;   // 7*1024 = 7168
  if (i < 7 * DINNER) {
    const int c = i & (DINNER - 1);
    const int k = i >> 10;
    wt[i] = w[c * 7 + k];
  }
}

// MFMA GEMM — 2-phase double-buffer with STATICALLY NAMED LDS buffers.
// SESSION LESSONS:
//  - R3's dbuf regression root cause: sA[2][..] with runtime cur index ->
//    hipcc alias analysis can't disambiguate in-flight global_load_lds
//    writes (buf cur^1) from ds_reads (buf cur) -> conservative vmcnt wait
//    BEFORE compute -> prefetch became serialization. This version uses
//    four distinct __shared__ arrays + a 2x-unrolled body so every LDS
//    access is a GEP into a named object (T3-minimum recipe, m230/m248:
//    2-phase in plain HIP measured 622-682 TF at 128 tile, refcheck'd).
//  - Each __syncthreads drain is now covered by 32 MFMA + 16 ds_read.
//  - launch_bounds (256,2) vs (256,3): measured identical (R6 A/B);
//    64 KiB LDS caps at 2 blocks/CU anyway.
//  - Scatter-heavy epilogues (R4 EPI3): ~+50 us per K=1024 dispatch. Gate
//    lives fully in-register in gemm_dual instead.
// C[m,n] = sum_k A[m,k]*B[n,k]; A: MxK, B: NxK, both row-major bf16.
// EPI 0: plain bf16 store
// EPI 2: +resid(f32), f32 store
// Requires K % 128 == 0 (even number of BK=64 tiles).
template <int EPI>
__global__ __launch_bounds__(256, 2) void gemm_bt(
    const bf16_t* __restrict__ A, const bf16_t* __restrict__ B,
    bf16_t* __restrict__ Cb, float* __restrict__ Cf,
    const float* __restrict__ resid,
    int N, int K)
{
  constexpr int BM = 128, BN = 128, BK = 64;
  __shared__ __attribute__((aligned(16))) bf16_t sA0[BM * BK];
  __shared__ __attribute__((aligned(16))) bf16_t sB0[BN * BK];
  __shared__ __attribute__((aligned(16))) bf16_t sA1[BM * BK];
  __shared__ __attribute__((aligned(16))) bf16_t sB1[BN * BK];

  const int tid  = threadIdx.x;
  const int bflat = xcd_swizzle_flat();
  const int m0 = (bflat / gridDim.x) * BM;
  const int n0 = (bflat % gridDim.x) * BN;

  const int w    = tid >> 6, lane = tid & 63;
  const int wm   = (w & 1) << 6, wn = (w >> 1) << 6;   // 2x2 waves -> 64x64 each
  const int quad = lane >> 4, lrow = lane & 15;

  // Per-thread staging geometry (constant across K-steps).
  const int f0 = tid << 3;                 // flat bf16 index, i=0 slice
  const int sr = f0 >> 6, sc = f0 & 63;    // row/col within 128x64 tile

  f32x4 acc[4][4] = {};

  auto STAGE = [&](int kt, bf16_t* dA, bf16_t* dB) {
#pragma unroll
    for (int i = 0; i < 4; ++i) {
      const int f = f0 + (i << 11);        // +i*256*8 bf16
      const int r = sr + (i << 5);         // +i*32 rows
      async_copy16(&A[(size_t)(m0 + r) * K + kt + sc], &dA[f]);
      async_copy16(&B[(size_t)(n0 + r) * K + kt + sc], &dB[f]);
    }
  };

  auto COMPUTE = [&](const bf16_t* cA, const bf16_t* cB) {
#pragma unroll
    for (int ks = 0; ks < 2; ++ks) {
      const int ko = ks * 32 + (quad << 3);
      bf16x8 av[4], bv[4];
#pragma unroll
      for (int i = 0; i < 4; ++i) {
        av[i] = *(const bf16x8*)&cA[(wm + i * 16 + lrow) * BK + ko];
        bv[i] = *(const bf16x8*)&cB[(wn + i * 16 + lrow) * BK + ko];
      }
#pragma unroll
      for (int mi = 0; mi < 4; ++mi)
#pragma unroll
        for (int ni = 0; ni < 4; ++ni)
          acc[mi][ni] = __builtin_amdgcn_mfma_f32_16x16x32_bf16(
              av[mi], bv[ni], acc[mi][ni], 0, 0, 0);
    }
  };

  // Prologue: stage tile 0 into buf0, single drain.
  STAGE(0, sA0, sB0);
  __syncthreads();

  // 2x-unrolled pipeline. Even tile lives in buf0, odd in buf1.
  for (int kt = 0; kt < K; kt += 2 * BK) {
    if (kt + BK < K) STAGE(kt + BK, sA1, sB1);   // prefetch odd tile
    COMPUTE(sA0, sB0);                           // compute even tile (covered)
    __syncthreads();                             // drain buf1 loads; buf0 free
    if (kt + 2 * BK < K) STAGE(kt + 2 * BK, sA0, sB0);
    COMPUTE(sA1, sB1);
    __syncthreads();
  }

  // C/D layout: col = lane&15, row = quad*4 + reg   [m89/m91 verified]
#pragma unroll
  for (int mi = 0; mi < 4; ++mi)
#pragma unroll
    for (int ni = 0; ni < 4; ++ni)
#pragma unroll
      for (int r = 0; r < 4; ++r) {
        const int row = m0 + wm + mi * 16 + (quad << 2) + r;
        const int col = n0 + wn + ni * 16 + lrow;
        float v = acc[mi][ni][r];
        if constexpr (EPI == 0) {
          Cb[(size_t)row * N + col] = (bf16_t)v;
        } else {
          v += resid[(size_t)row * N + col];
          Cf[(size_t)row * N + col] = v;
        }
      }
}

// Fused dual GEMM + gate (steps 3+5+6) — UNCHANGED this round (control
// for the dbuf A/B in gemm_bt):
//   sf = silu(A1 @ B1^T + b1)   (in registers, never touches HBM)
//   sb = silu(A2 @ B2^T + b2)   (in registers)
//   G  = (sf*[t>0] + sb*[t<T-1] + xp*diag) * silu(z) * gs
// Measured (R7): ~126 us/chunk, MfmaUtil 22.6, FETCH 98.7 MB (compulsory).
__global__ __launch_bounds__(256, 2) void gemm_dual(
    const bf16_t* __restrict__ A1, const bf16_t* __restrict__ A2,
    const bf16_t* __restrict__ B1, const bf16_t* __restrict__ B2,
    const float* __restrict__ b1, const float* __restrict__ b2,
    const bf16_t* __restrict__ xzc, const float* __restrict__ diag,
    const float* __restrict__ gs, bf16_t* __restrict__ G,
    int r0, int loc0, int N, int K)
{
  constexpr int BM = 128, BN = 128, BK = 64;
  __shared__ __attribute__((aligned(16))) bf16_t sA1[BM * BK];
  __shared__ __attribute__((aligned(16))) bf16_t sA2[BM * BK];
  __shared__ __attribute__((aligned(16))) bf16_t sB1[BN * BK];
  __shared__ __attribute__((aligned(16))) bf16_t sB2[BN * BK];

  const int tid  = threadIdx.x;
  const int bflat = xcd_swizzle_flat();
  const int m0 = (bflat / gridDim.x) * BM;
  const int n0 = (bflat % gridDim.x) * BN;

  const int w    = tid >> 6, lane = tid & 63;
  const int wm   = (w & 1) << 6, wn = (w >> 1) << 6;
  const int quad = lane >> 4, lrow = lane & 15;

  f32x4 accf[4][4] = {};
  f32x4 accb[4][4] = {};

  for (int kt = 0; kt < K; kt += BK) {
    __syncthreads();
#pragma unroll
    for (int i = 0; i < 4; ++i) {
      const int f = (i * 256 + tid) << 3;
      const int r = f >> 6, c = f & 63;
      const size_t ga = (size_t)(m0 + r) * K + kt + c;
      const size_t gb = (size_t)(n0 + r) * K + kt + c;
      async_copy16(&A1[ga], &sA1[f]);
      async_copy16(&A2[ga], &sA2[f]);
      async_copy16(&B1[gb], &sB1[f]);
      async_copy16(&B2[gb], &sB2[f]);
    }
    __syncthreads();
#pragma unroll
    for (int ks = 0; ks < 2; ++ks) {
      const int ko = ks * 32 + (quad << 3);
      bf16x8 av[4], bv[4];
#pragma unroll
      for (int i = 0; i < 4; ++i) {
        av[i] = *(const bf16x8*)&sA1[(wm + i * 16 + lrow) * BK + ko];
        bv[i] = *(const bf16x8*)&sB1[(wn + i * 16 + lrow) * BK + ko];
      }
#pragma unroll
      for (int mi = 0; mi < 4; ++mi)
#pragma unroll
        for (int ni = 0; ni < 4; ++ni)
          accf[mi][ni] = __builtin_amdgcn_mfma_f32_16x16x32_bf16(
              av[mi], bv[ni], accf[mi][ni], 0, 0, 0);
#pragma unroll
      for (int i = 0; i < 4; ++i) {
        av[i] = *(const bf16x8*)&sA2[(wm + i * 16 + lrow) * BK + ko];
        bv[i] = *(const bf16x8*)&sB2[(wn + i * 16 + lrow) * BK + ko];
      }
#pragma unroll
      for (int mi = 0; mi < 4; ++mi)
#pragma unroll
        for (int ni = 0; ni < 4; ++ni)
          accb[mi][ni] = __builtin_amdgcn_mfma_f32_16x16x32_bf16(
              av[mi], bv[ni], accb[mi][ni], 0, 0, 0);
    }
  }

  // Epilogue: per-element gate, all in registers.
  const float gsv = gs[0];
  int   colv[4];
  float b1v[4], b2v[4], dgv[4];
#pragma unroll
  for (int ni = 0; ni < 4; ++ni) {
    const int col = n0 + wn + ni * 16 + lrow;
    colv[ni] = col;
    b1v[ni] = b1[col];
    b2v[ni] = b2[col];
    dgv[ni] = diag[col];
  }
#pragma unroll
  for (int mi = 0; mi < 4; ++mi)
#pragma unroll
    for (int r = 0; r < 4; ++r) {
      const int row = m0 + wm + mi * 16 + (quad << 2) + r;
      const int t = (row + r0) & (T_SEQ - 1);
      const bool tf = (t > 0), tb = (t < T_SEQ - 1);
      const bf16_t* xrow = &xzc[(size_t)(loc0 + row) * 2048];
#pragma unroll
      for (int ni = 0; ni < 4; ++ni) {
        const float sf = silu_f(accf[mi][ni][r] + b1v[ni]);
        const float sb = silu_f(accb[mi][ni][r] + b2v[ni]);
        const float xp = (float)xrow[colv[ni]];
        const float z  = (float)xrow[colv[ni] + DINNER];
        float y = xp * dgv[ni];
        if (tf) y += sf;
        if (tb) y += sb;
        G[(size_t)row * N + colv[ni]] = (bf16_t)(y * silu_f(z) * gsv);
      }
    }
}

// Depthwise causal conv, one direction, shift_right folded in.
// Register-blocked + vectorized: each thread = 4 consecutive t x 8 channels.
template <int DIR>
__global__ __launch_bounds__(256) void conv_kernel(
    const bf16_t* __restrict__ xzc,
    const float* __restrict__ wt, const float* __restrict__ bc,
    bf16_t* __restrict__ vout, int r0, int loc0, int Mc)
{
  const int idx = blockIdx.x * 256 + threadIdx.x;   // over CH*DINNER/32
  const int c8  = idx & 127;                        // 8-channel group
  const int tg  = idx >> 7;                         // 4-row time group
  const int bt0 = tg << 2;                          // chunk-local first row
  const int t0  = (bt0 + r0) & (T_SEQ - 1);         // in-sequence t of first row
  const int lt0 = bt0 + loc0;                       // local row in xzc
  const int cc  = c8 << 3;

  float wv[7][8];
#pragma unroll
  for (int k = 0; k < 7; ++k) {
    const f32x4 a = *(const f32x4*)&wt[k * DINNER + cc];
    const f32x4 b = *(const f32x4*)&wt[k * DINNER + cc + 4];
#pragma unroll
    for (int u = 0; u < 4; ++u) { wv[k][u] = a[u]; wv[k][u + 4] = b[u]; }
  }

  float acc[4][8];
  {
    const f32x4 a = *(const f32x4*)&bc[cc];
    const f32x4 b = *(const f32x4*)&bc[cc + 4];
#pragma unroll
    for (int i = 0; i < 4; ++i)
#pragma unroll
      for (int u = 0; u < 4; ++u) { acc[i][u] = a[u]; acc[i][u + 4] = b[u]; }
  }

#pragma unroll
  for (int rr = 0; rr < 10; ++rr) {
    int lt = (DIR == 0) ? (lt0 - 7 + rr) : (lt0 + 1 + rr);
    lt = lt < 0 ? 0 : (lt > Mc - 1 ? Mc - 1 : lt);
    const bf16x8 xv = *(const bf16x8*)&xzc[(size_t)lt * 2048 + cc];
    float xf[8];
#pragma unroll
    for (int u = 0; u < 8; ++u) xf[u] = (float)xv[u];
#pragma unroll
    for (int i = 0; i < 4; ++i) {
      const int k = (DIR == 0) ? (rr - i) : (i + 6 - rr);
      if (k >= 0 && k <= 6) {
        const bool ok = (DIR == 0) ? (t0 + i >= 7 - k)
                                   : (t0 + i <= (T_SEQ - 8) + k);
        if (ok) {
#pragma unroll
          for (int u = 0; u < 8; ++u) acc[i][u] += wv[k][u] * xf[u];
        }
      }
    }
  }

#pragma unroll
  for (int i = 0; i < 4; ++i) {
    bf16x8 o;
#pragma unroll
    for (int u = 0; u < 8; ++u) o[u] = (bf16_t)acc[i][u];
    *(bf16x8*)&vout[(size_t)(bt0 + i) * DINNER + cc] = o;
  }
}

// LayerNorm over D=512, one block (256 threads) per chunk-local row.
__global__ __launch_bounds__(256) void ln_kernel(
    const float* __restrict__ h,
    const float* __restrict__ lng, const float* __restrict__ lnb,
    float* __restrict__ out, int r0)
{
  const int row = blockIdx.x;                        // local row
  const int tid = threadIdx.x;
  const float* hr = h + (size_t)row * DMODEL;
  const float v0 = hr[tid], v1 = hr[tid + 256];
  float s  = v0 + v1;
  float ss = v0 * v0 + v1 * v1;
#pragma unroll
  for (int off = 1; off < 64; off <<= 1) {
    s  += __shfl_xor(s, off);
    ss += __shfl_xor(ss, off);
  }
  __shared__ float ps[8];
  const int w = tid >> 6;
  if ((tid & 63) == 0) { ps[w] = s; ps[w + 4] = ss; }
  __syncthreads();
  s  = ps[0] + ps[1] + ps[2] + ps[3];
  ss = ps[4] + ps[5] + ps[6] + ps[7];
  const float mu  = s * (1.f / DMODEL);
  const float inv = rsqrtf(ss * (1.f / DMODEL) - mu * mu + 1e-5f);
  float* o = out + (size_t)(r0 + row) * DMODEL;
  o[tid]       = (v0 - mu) * inv * lng[tid]       + lnb[tid];
  o[tid + 256] = (v1 - mu) * inv * lng[tid + 256] + lnb[tid + 256];
}

extern "C" void kernel_launch(void* const* d_in, const int* in_sizes, int n_in,
                              void* d_out, int out_size, void* d_ws, size_t ws_size,
                              hipStream_t stream) {
  const float* x    = (const float*)d_in[0];
  const float* in_w = (const float*)d_in[1];
  const float* cfw  = (const float*)d_in[2];
  const float* cfb  = (const float*)d_in[3];
  const float* pfw  = (const float*)d_in[4];
  const float* pfb  = (const float*)d_in[5];
  const float* cbw  = (const float*)d_in[6];
  const float* cbb  = (const float*)d_in[7];
  const float* pbw  = (const float*)d_in[8];
  const float* pbb  = (const float*)d_in[9];
  const float* diag = (const float*)d_in[10];
  const float* gs   = (const float*)d_in[11];
  const float* ow   = (const float*)d_in[12];
  const float* lng  = (const float*)d_in[13];
  const float* lnb  = (const float*)d_in[14];
  float* out = (float*)d_out;

  char* ws = (char*)d_ws;

  // Persistent bf16 copies of GEMM operand tensors + transposed conv weights:
  bf16_t* xw   = (bf16_t*)(ws);                         // 32768x512   (32 MiB)
  bf16_t* inwb = (bf16_t*)(ws + (size_t)33554432);      // 2048x512    (2 MiB)
  bf16_t* pfwb = (bf16_t*)(ws + (size_t)35651584);      // 1024x1024   (2 MiB)
  bf16_t* pbwb = (bf16_t*)(ws + (size_t)37748736);      // 1024x1024   (2 MiB)
  bf16_t* owb  = (bf16_t*)(ws + (size_t)39845888);      // 512x1024    (1 MiB)
  float*  wtf  = (float*)(ws + (size_t)40894464);       // 7x1024 f32  (28 KiB)
  float*  wtb  = (float*)(ws + (size_t)40923136);       // 7x1024 f32  (28 KiB)
  const size_t persist = 40951808;

  // Workspace-adaptive chunking. (Observed: CH=16384 fits -> 2 chunks.)
  // req(CH) = persist + (CH+256)*4096 + 3*CH*2048 bytes
  int CH = 128;
  {
    const int cands[9] = {32768, 16384, 8192, 4096, 2048, 1024, 512, 256, 128};
    for (int i = 0; i < 9; ++i) {
      const size_t req = persist + (size_t)(cands[i] + 256) * 4096 +
                         (size_t)3 * cands[i] * 2048;
      if (ws_size >= req) { CH = cands[i]; break; }
    }
  }

  char* cb = ws + persist;
  const size_t xz_cap = (size_t)(CH + 256) * 4096;      // bytes
  bf16_t* xzc  = (bf16_t*)cb;
  bf16_t* bufA = (bf16_t*)(cb + xz_cap);                      // v_fwd
  bf16_t* bufB = (bf16_t*)(cb + xz_cap + (size_t)CH * 2048);  // v_bwd
  bf16_t* bufC = (bf16_t*)(cb + xz_cap + (size_t)CH * 4096);  // g
  float*  hbuf = (float*)cb;                             // aliases xzc (dead by then)

  dim3 blk(256);

  // 0) one-time fp32 -> bf16 casts of GEMM operands + conv-weight transposes
  cast_kernel<<<dim3(16384), blk, 0, stream>>>(x,    xw,   4194304);
  cast_kernel<<<dim3(1024),  blk, 0, stream>>>(in_w, inwb, 262144);
  cast_kernel<<<dim3(1024),  blk, 0, stream>>>(pfw,  pfwb, 262144);
  cast_kernel<<<dim3(1024),  blk, 0, stream>>>(pbw,  pbwb, 262144);
  cast_kernel<<<dim3(512),   blk, 0, stream>>>(ow,   owb,  131072);
  wtr_kernel<<<dim3(28), blk, 0, stream>>>(cfw, wtf);
  wtr_kernel<<<dim3(28), blk, 0, stream>>>(cbw, wtb);

  for (int r0 = 0; r0 < MTOT; r0 += CH) {
    const int g0 = (r0 >= 128) ? (r0 - 128) : 0;
    int g1 = r0 + CH + 128; if (g1 > MTOT) g1 = MTOT;
    const int Mc   = g1 - g0;        // multiple of 128
    const int loc0 = r0 - g0;        // chunk start's local row in xzc

    // 1) xzc = x[g0:g1] @ in_proj_w^T        (Mc x 2048, K=512)
    gemm_bt<0><<<dim3(2048 / 128, Mc / 128), blk, 0, stream>>>(
        xw + (size_t)g0 * 512, inwb, xzc, nullptr, nullptr, 2048, 512);

    // 2) forward shifted causal conv -> v_fwd (bufA)
    conv_kernel<0><<<dim3(CH / 8), blk, 0, stream>>>(
        xzc, wtf, cfb, bufA, r0, loc0, Mc);

    // 3) backward shifted causal conv -> v_bwd (bufB)
    conv_kernel<1><<<dim3(CH / 8), blk, 0, stream>>>(
        xzc, wtb, cbb, bufB, r0, loc0, Mc);

    // 4) fused: sf/sb GEMMs + gate -> g (bufC)
    gemm_dual<<<dim3(1024 / 128, CH / 128), blk, 0, stream>>>(
        bufA, bufB, pfwb, pbwb, pfb, pbb, xzc, diag, gs, bufC,
        r0, loc0, 1024, 1024);

    // 5) h = x + g @ out_proj^T (fp32) -> hbuf (aliases xzc; xz dead now)
    gemm_bt<2><<<dim3(512 / 128, CH / 128), blk, 0, stream>>>(
        bufC, owb, nullptr, hbuf, x + (size_t)r0 * 512, 512, 1024);

    // 6) LayerNorm -> out rows [r0, r0+CH)   (fp32 store)
    ln_kernel<<<dim3(CH), blk, 0, stream>>>(hbuf, lng, lnb, out, r0);
  }
}

// Round 9
// 621.919 us; speedup vs baseline: 1.1885x; 1.0319x over previous
//
#include <hip/hip_runtime.h>
#include <hip/hip_bf16.h>
#include <cstdint>

// Problem constants
#define T_SEQ  4096
#define DMODEL 512
#define DINNER 1024
#define MTOT   32768            // B*T = 8*4096 rows

typedef __bf16 bf16_t;
typedef bf16_t bf16x8 __attribute__((ext_vector_type(8)));
typedef bf16_t bf16x4v __attribute__((ext_vector_type(4)));
typedef float  f32x4  __attribute__((ext_vector_type(4)));

__device__ __forceinline__ void async_copy16(const bf16_t* g, bf16_t* l) {
  __builtin_amdgcn_global_load_lds(
      (const __attribute__((address_space(1))) void*)g,
      (__attribute__((address_space(3))) void*)l,
      16, 0, 0);
}

__device__ __forceinline__ float silu_f(float v) {
  return v / (1.f + __expf(-v));
}

// T1: bijective XCD-aware block swizzle (m204 form).
__device__ __forceinline__ int xcd_swizzle_flat() {
  const int nwg = gridDim.x * gridDim.y;
  const int orig = blockIdx.y * gridDim.x + blockIdx.x;
  const int q = nwg >> 3, r = nwg & 7;
  const int xcd = orig & 7, lid = orig >> 3;
  return (xcd < r ? xcd * (q + 1) : r * (q + 1) + (xcd - r) * q) + lid;
}

// fp32 -> bf16 cast, 4 elements/thread
__global__ __launch_bounds__(256) void cast_kernel(
    const float* __restrict__ s, bf16_t* __restrict__ d, int n4)
{
  const int i = blockIdx.x * 256 + threadIdx.x;
  if (i < n4) {
    const f32x4 v = ((const f32x4*)s)[i];
    bf16x4v o;
    o[0] = (bf16_t)v[0]; o[1] = (bf16_t)v[1];
    o[2] = (bf16_t)v[2]; o[3] = (bf16_t)v[3];
    ((bf16x4v*)d)[i] = o;
  }
}

// Transpose conv weight (DINNER,1,7) [c][k] -> wt[k][c] (7 x 1024 f32)
__global__ __launch_bounds__(256) void wtr_kernel(
    const float* __restrict__ w, float* __restrict__ wt)
{
  const int i = blockIdx.x * 256 + threadIdx.x;   // 7*1024 = 7168
  if (i < 7 * DINNER) {
    const int c = i & (DINNER - 1);
    const int k = i >> 10;
    wt[i] = w[c * 7 + k];
  }
}

// MFMA GEMM — 2-phase double-buffer with STATICALLY NAMED LDS buffers.
// R8 VERIFIED: distinct named __shared__ arrays (not runtime-indexed
// sA[cur]) let hipcc disambiguate in-flight global_load_lds writes from
// ds_reads -> real prefetch overlap, no serialization (R3's failure was
// the runtime index). 648.8 -> 641.8 total with gemm_dual as control.
// C[m,n] = sum_k A[m,k]*B[n,k]; A: MxK, B: NxK, both row-major bf16.
// EPI 0: plain bf16 store
// EPI 2: +resid(f32), f32 store
// Requires K % 128 == 0 (even number of BK=64 tiles).
template <int EPI>
__global__ __launch_bounds__(256, 2) void gemm_bt(
    const bf16_t* __restrict__ A, const bf16_t* __restrict__ B,
    bf16_t* __restrict__ Cb, float* __restrict__ Cf,
    const float* __restrict__ resid,
    int N, int K)
{
  constexpr int BM = 128, BN = 128, BK = 64;
  __shared__ __attribute__((aligned(16))) bf16_t sA0[BM * BK];
  __shared__ __attribute__((aligned(16))) bf16_t sB0[BN * BK];
  __shared__ __attribute__((aligned(16))) bf16_t sA1[BM * BK];
  __shared__ __attribute__((aligned(16))) bf16_t sB1[BN * BK];

  const int tid  = threadIdx.x;
  const int bflat = xcd_swizzle_flat();
  const int m0 = (bflat / gridDim.x) * BM;
  const int n0 = (bflat % gridDim.x) * BN;

  const int w    = tid >> 6, lane = tid & 63;
  const int wm   = (w & 1) << 6, wn = (w >> 1) << 6;   // 2x2 waves -> 64x64 each
  const int quad = lane >> 4, lrow = lane & 15;

  // Per-thread staging geometry (constant across K-steps).
  const int f0 = tid << 3;                 // flat bf16 index, i=0 slice
  const int sr = f0 >> 6, sc = f0 & 63;    // row/col within 128x64 tile

  f32x4 acc[4][4] = {};

  auto STAGE = [&](int kt, bf16_t* dA, bf16_t* dB) {
#pragma unroll
    for (int i = 0; i < 4; ++i) {
      const int f = f0 + (i << 11);        // +i*256*8 bf16
      const int r = sr + (i << 5);         // +i*32 rows
      async_copy16(&A[(size_t)(m0 + r) * K + kt + sc], &dA[f]);
      async_copy16(&B[(size_t)(n0 + r) * K + kt + sc], &dB[f]);
    }
  };

  auto COMPUTE = [&](const bf16_t* cA, const bf16_t* cB) {
#pragma unroll
    for (int ks = 0; ks < 2; ++ks) {
      const int ko = ks * 32 + (quad << 3);
      bf16x8 av[4], bv[4];
#pragma unroll
      for (int i = 0; i < 4; ++i) {
        av[i] = *(const bf16x8*)&cA[(wm + i * 16 + lrow) * BK + ko];
        bv[i] = *(const bf16x8*)&cB[(wn + i * 16 + lrow) * BK + ko];
      }
#pragma unroll
      for (int mi = 0; mi < 4; ++mi)
#pragma unroll
        for (int ni = 0; ni < 4; ++ni)
          acc[mi][ni] = __builtin_amdgcn_mfma_f32_16x16x32_bf16(
              av[mi], bv[ni], acc[mi][ni], 0, 0, 0);
    }
  };

  // Prologue: stage tile 0 into buf0, single drain.
  STAGE(0, sA0, sB0);
  __syncthreads();

  // 2x-unrolled pipeline. Even tile lives in buf0, odd in buf1.
  for (int kt = 0; kt < K; kt += 2 * BK) {
    if (kt + BK < K) STAGE(kt + BK, sA1, sB1);   // prefetch odd tile
    COMPUTE(sA0, sB0);                           // compute even tile (covered)
    __syncthreads();                             // drain buf1 loads; buf0 free
    if (kt + 2 * BK < K) STAGE(kt + 2 * BK, sA0, sB0);
    COMPUTE(sA1, sB1);
    __syncthreads();
  }

  // C/D layout: col = lane&15, row = quad*4 + reg   [m89/m91 verified]
#pragma unroll
  for (int mi = 0; mi < 4; ++mi)
#pragma unroll
    for (int ni = 0; ni < 4; ++ni)
#pragma unroll
      for (int r = 0; r < 4; ++r) {
        const int row = m0 + wm + mi * 16 + (quad << 2) + r;
        const int col = n0 + wn + ni * 16 + lrow;
        float v = acc[mi][ni][r];
        if constexpr (EPI == 0) {
          Cb[(size_t)row * N + col] = (bf16_t)v;
        } else {
          v += resid[(size_t)row * N + col];
          Cf[(size_t)row * N + col] = v;
        }
      }
}

// Fused dual GEMM + gate (steps 3+5+6), NOW 2-PHASE PIPELINED:
//   sf = silu(A1 @ B1^T + b1)   (in registers, never touches HBM)
//   sb = silu(A2 @ B2^T + b2)   (in registers)
//   G  = (sf*[t>0] + sb*[t<T-1] + xp*diag) * silu(z) * gs
// The two independent compute phases per K-step (fwd on sA1/sB1, bwd on
// sA2/sB2) allow pipelining WITHOUT doubling LDS (stays 64 KiB, 2 blk/CU):
//   phase A: issue stage A2/B2[kt]   ; compute fwd[kt] (32 MFMA cover); bar
//   phase B: issue stage A1/B1[kt+64]; compute bwd[kt]                ; bar
// Every vmcnt(0) drain is covered by a full MFMA phase (was: uncovered
// 16-load drain per K-step). Same statically-named-buffer discipline
// that R8 proved safe in gemm_bt.
__global__ __launch_bounds__(256, 2) void gemm_dual(
    const bf16_t* __restrict__ A1, const bf16_t* __restrict__ A2,
    const bf16_t* __restrict__ B1, const bf16_t* __restrict__ B2,
    const float* __restrict__ b1, const float* __restrict__ b2,
    const bf16_t* __restrict__ xzc, const float* __restrict__ diag,
    const float* __restrict__ gs, bf16_t* __restrict__ G,
    int r0, int loc0, int N, int K)
{
  constexpr int BM = 128, BN = 128, BK = 64;
  __shared__ __attribute__((aligned(16))) bf16_t sA1l[BM * BK];
  __shared__ __attribute__((aligned(16))) bf16_t sA2l[BM * BK];
  __shared__ __attribute__((aligned(16))) bf16_t sB1l[BN * BK];
  __shared__ __attribute__((aligned(16))) bf16_t sB2l[BN * BK];

  const int tid  = threadIdx.x;
  const int bflat = xcd_swizzle_flat();
  const int m0 = (bflat / gridDim.x) * BM;
  const int n0 = (bflat % gridDim.x) * BN;

  const int w    = tid >> 6, lane = tid & 63;
  const int wm   = (w & 1) << 6, wn = (w >> 1) << 6;
  const int quad = lane >> 4, lrow = lane & 15;

  const int f0 = tid << 3;
  const int sr = f0 >> 6, sc = f0 & 63;

  f32x4 accf[4][4] = {};
  f32x4 accb[4][4] = {};

  // Stage one operand pair (gA -> dA, gB -> dB) for K-offset kt.
  auto STAGE = [&](int kt, const bf16_t* gA, const bf16_t* gB,
                   bf16_t* dA, bf16_t* dB) {
#pragma unroll
    for (int i = 0; i < 4; ++i) {
      const int f = f0 + (i << 11);
      const int r = sr + (i << 5);
      async_copy16(&gA[(size_t)(m0 + r) * K + kt + sc], &dA[f]);
      async_copy16(&gB[(size_t)(n0 + r) * K + kt + sc], &dB[f]);
    }
  };

  auto COMPUTE = [&](const bf16_t* cA, const bf16_t* cB, f32x4 (*acc)[4]) {
#pragma unroll
    for (int ks = 0; ks < 2; ++ks) {
      const int ko = ks * 32 + (quad << 3);
      bf16x8 av[4], bv[4];
#pragma unroll
      for (int i = 0; i < 4; ++i) {
        av[i] = *(const bf16x8*)&cA[(wm + i * 16 + lrow) * BK + ko];
        bv[i] = *(const bf16x8*)&cB[(wn + i * 16 + lrow) * BK + ko];
      }
#pragma unroll
      for (int mi = 0; mi < 4; ++mi)
#pragma unroll
        for (int ni = 0; ni < 4; ++ni)
          acc[mi][ni] = __builtin_amdgcn_mfma_f32_16x16x32_bf16(
              av[mi], bv[ni], acc[mi][ni], 0, 0, 0);
    }
  };

  // Prologue: stage fwd operands of tile 0; drain.
  STAGE(0, A1, B1, sA1l, sB1l);
  __syncthreads();

  for (int kt = 0; kt < K; kt += BK) {
    STAGE(kt, A2, B2, sA2l, sB2l);            // issue bwd[kt] loads
    COMPUTE(sA1l, sB1l, accf);                // fwd[kt] covers them
    __syncthreads();                          // bwd[kt] ready; sA1l/sB1l free
    if (kt + BK < K) STAGE(kt + BK, A1, B1, sA1l, sB1l);  // issue fwd[kt+1]
    COMPUTE(sA2l, sB2l, accb);                // bwd[kt] covers them
    __syncthreads();                          // fwd[kt+1] ready; sA2l/sB2l free
  }

  // Epilogue: per-element gate, all in registers.
  const float gsv = gs[0];
  int   colv[4];
  float b1v[4], b2v[4], dgv[4];
#pragma unroll
  for (int ni = 0; ni < 4; ++ni) {
    const int col = n0 + wn + ni * 16 + lrow;
    colv[ni] = col;
    b1v[ni] = b1[col];
    b2v[ni] = b2[col];
    dgv[ni] = diag[col];
  }
#pragma unroll
  for (int mi = 0; mi < 4; ++mi)
#pragma unroll
    for (int r = 0; r < 4; ++r) {
      const int row = m0 + wm + mi * 16 + (quad << 2) + r;
      const int t = (row + r0) & (T_SEQ - 1);
      const bool tf = (t > 0), tb = (t < T_SEQ - 1);
      const bf16_t* xrow = &xzc[(size_t)(loc0 + row) * 2048];
#pragma unroll
      for (int ni = 0; ni < 4; ++ni) {
        const float sf = silu_f(accf[mi][ni][r] + b1v[ni]);
        const float sb = silu_f(accb[mi][ni][r] + b2v[ni]);
        const float xp = (float)xrow[colv[ni]];
        const float z  = (float)xrow[colv[ni] + DINNER];
        float y = xp * dgv[ni];
        if (tf) y += sf;
        if (tb) y += sb;
        G[(size_t)row * N + colv[ni]] = (bf16_t)(y * silu_f(z) * gsv);
      }
    }
}

// Depthwise causal conv, one direction, shift_right folded in.
// Register-blocked + vectorized: each thread = 4 consecutive t x 8 channels.
template <int DIR>
__global__ __launch_bounds__(256) void conv_kernel(
    const bf16_t* __restrict__ xzc,
    const float* __restrict__ wt, const float* __restrict__ bc,
    bf16_t* __restrict__ vout, int r0, int loc0, int Mc)
{
  const int idx = blockIdx.x * 256 + threadIdx.x;   // over CH*DINNER/32
  const int c8  = idx & 127;                        // 8-channel group
  const int tg  = idx >> 7;                         // 4-row time group
  const int bt0 = tg << 2;                          // chunk-local first row
  const int t0  = (bt0 + r0) & (T_SEQ - 1);         // in-sequence t of first row
  const int lt0 = bt0 + loc0;                       // local row in xzc
  const int cc  = c8 << 3;

  float wv[7][8];
#pragma unroll
  for (int k = 0; k < 7; ++k) {
    const f32x4 a = *(const f32x4*)&wt[k * DINNER + cc];
    const f32x4 b = *(const f32x4*)&wt[k * DINNER + cc + 4];
#pragma unroll
    for (int u = 0; u < 4; ++u) { wv[k][u] = a[u]; wv[k][u + 4] = b[u]; }
  }

  float acc[4][8];
  {
    const f32x4 a = *(const f32x4*)&bc[cc];
    const f32x4 b = *(const f32x4*)&bc[cc + 4];
#pragma unroll
    for (int i = 0; i < 4; ++i)
#pragma unroll
      for (int u = 0; u < 4; ++u) { acc[i][u] = a[u]; acc[i][u + 4] = b[u]; }
  }

#pragma unroll
  for (int rr = 0; rr < 10; ++rr) {
    int lt = (DIR == 0) ? (lt0 - 7 + rr) : (lt0 + 1 + rr);
    lt = lt < 0 ? 0 : (lt > Mc - 1 ? Mc - 1 : lt);
    const bf16x8 xv = *(const bf16x8*)&xzc[(size_t)lt * 2048 + cc];
    float xf[8];
#pragma unroll
    for (int u = 0; u < 8; ++u) xf[u] = (float)xv[u];
#pragma unroll
    for (int i = 0; i < 4; ++i) {
      const int k = (DIR == 0) ? (rr - i) : (i + 6 - rr);
      if (k >= 0 && k <= 6) {
        const bool ok = (DIR == 0) ? (t0 + i >= 7 - k)
                                   : (t0 + i <= (T_SEQ - 8) + k);
        if (ok) {
#pragma unroll
          for (int u = 0; u < 8; ++u) acc[i][u] += wv[k][u] * xf[u];
        }
      }
    }
  }

#pragma unroll
  for (int i = 0; i < 4; ++i) {
    bf16x8 o;
#pragma unroll
    for (int u = 0; u < 8; ++u) o[u] = (bf16_t)acc[i][u];
    *(bf16x8*)&vout[(size_t)(bt0 + i) * DINNER + cc] = o;
  }
}

// LayerNorm over D=512, one block (256 threads) per chunk-local row.
__global__ __launch_bounds__(256) void ln_kernel(
    const float* __restrict__ h,
    const float* __restrict__ lng, const float* __restrict__ lnb,
    float* __restrict__ out, int r0)
{
  const int row = blockIdx.x;                        // local row
  const int tid = threadIdx.x;
  const float* hr = h + (size_t)row * DMODEL;
  const float v0 = hr[tid], v1 = hr[tid + 256];
  float s  = v0 + v1;
  float ss = v0 * v0 + v1 * v1;
#pragma unroll
  for (int off = 1; off < 64; off <<= 1) {
    s  += __shfl_xor(s, off);
    ss += __shfl_xor(ss, off);
  }
  __shared__ float ps[8];
  const int w = tid >> 6;
  if ((tid & 63) == 0) { ps[w] = s; ps[w + 4] = ss; }
  __syncthreads();
  s  = ps[0] + ps[1] + ps[2] + ps[3];
  ss = ps[4] + ps[5] + ps[6] + ps[7];
  const float mu  = s * (1.f / DMODEL);
  const float inv = rsqrtf(ss * (1.f / DMODEL) - mu * mu + 1e-5f);
  float* o = out + (size_t)(r0 + row) * DMODEL;
  o[tid]       = (v0 - mu) * inv * lng[tid]       + lnb[tid];
  o[tid + 256] = (v1 - mu) * inv * lng[tid + 256] + lnb[tid + 256];
}

extern "C" void kernel_launch(void* const* d_in, const int* in_sizes, int n_in,
                              void* d_out, int out_size, void* d_ws, size_t ws_size,
                              hipStream_t stream) {
  const float* x    = (const float*)d_in[0];
  const float* in_w = (const float*)d_in[1];
  const float* cfw  = (const float*)d_in[2];
  const float* cfb  = (const float*)d_in[3];
  const float* pfw  = (const float*)d_in[4];
  const float* pfb  = (const float*)d_in[5];
  const float* cbw  = (const float*)d_in[6];
  const float* cbb  = (const float*)d_in[7];
  const float* pbw  = (const float*)d_in[8];
  const float* pbb  = (const float*)d_in[9];
  const float* diag = (const float*)d_in[10];
  const float* gs   = (const float*)d_in[11];
  const float* ow   = (const float*)d_in[12];
  const float* lng  = (const float*)d_in[13];
  const float* lnb  = (const float*)d_in[14];
  float* out = (float*)d_out;

  char* ws = (char*)d_ws;

  // Persistent bf16 copies of GEMM operand tensors + transposed conv weights:
  bf16_t* xw   = (bf16_t*)(ws);                         // 32768x512   (32 MiB)
  bf16_t* inwb = (bf16_t*)(ws + (size_t)33554432);      // 2048x512    (2 MiB)
  bf16_t* pfwb = (bf16_t*)(ws + (size_t)35651584);      // 1024x1024   (2 MiB)
  bf16_t* pbwb = (bf16_t*)(ws + (size_t)37748736);      // 1024x1024   (2 MiB)
  bf16_t* owb  = (bf16_t*)(ws + (size_t)39845888);      // 512x1024    (1 MiB)
  float*  wtf  = (float*)(ws + (size_t)40894464);       // 7x1024 f32  (28 KiB)
  float*  wtb  = (float*)(ws + (size_t)40923136);       // 7x1024 f32  (28 KiB)
  const size_t persist = 40951808;

  // Workspace-adaptive chunking. (Observed: CH=16384 fits -> 2 chunks.)
  // req(CH) = persist + (CH+256)*4096 + 3*CH*2048 bytes
  int CH = 128;
  {
    const int cands[9] = {32768, 16384, 8192, 4096, 2048, 1024, 512, 256, 128};
    for (int i = 0; i < 9; ++i) {
      const size_t req = persist + (size_t)(cands[i] + 256) * 4096 +
                         (size_t)3 * cands[i] * 2048;
      if (ws_size >= req) { CH = cands[i]; break; }
    }
  }

  char* cb = ws + persist;
  const size_t xz_cap = (size_t)(CH + 256) * 4096;      // bytes
  bf16_t* xzc  = (bf16_t*)cb;
  bf16_t* bufA = (bf16_t*)(cb + xz_cap);                      // v_fwd
  bf16_t* bufB = (bf16_t*)(cb + xz_cap + (size_t)CH * 2048);  // v_bwd
  bf16_t* bufC = (bf16_t*)(cb + xz_cap + (size_t)CH * 4096);  // g
  float*  hbuf = (float*)cb;                             // aliases xzc (dead by then)

  dim3 blk(256);

  // 0) one-time fp32 -> bf16 casts of GEMM operands + conv-weight transposes
  cast_kernel<<<dim3(16384), blk, 0, stream>>>(x,    xw,   4194304);
  cast_kernel<<<dim3(1024),  blk, 0, stream>>>(in_w, inwb, 262144);
  cast_kernel<<<dim3(1024),  blk, 0, stream>>>(pfw,  pfwb, 262144);
  cast_kernel<<<dim3(1024),  blk, 0, stream>>>(pbw,  pbwb, 262144);
  cast_kernel<<<dim3(512),   blk, 0, stream>>>(ow,   owb,  131072);
  wtr_kernel<<<dim3(28), blk, 0, stream>>>(cfw, wtf);
  wtr_kernel<<<dim3(28), blk, 0, stream>>>(cbw, wtb);

  for (int r0 = 0; r0 < MTOT; r0 += CH) {
    const int g0 = (r0 >= 128) ? (r0 - 128) : 0;
    int g1 = r0 + CH + 128; if (g1 > MTOT) g1 = MTOT;
    const int Mc   = g1 - g0;        // multiple of 128
    const int loc0 = r0 - g0;        // chunk start's local row in xzc

    // 1) xzc = x[g0:g1] @ in_proj_w^T        (Mc x 2048, K=512)
    gemm_bt<0><<<dim3(2048 / 128, Mc / 128), blk, 0, stream>>>(
        xw + (size_t)g0 * 512, inwb, xzc, nullptr, nullptr, 2048, 512);

    // 2) forward shifted causal conv -> v_fwd (bufA)
    conv_kernel<0><<<dim3(CH / 8), blk, 0, stream>>>(
        xzc, wtf, cfb, bufA, r0, loc0, Mc);

    // 3) backward shifted causal conv -> v_bwd (bufB)
    conv_kernel<1><<<dim3(CH / 8), blk, 0, stream>>>(
        xzc, wtb, cbb, bufB, r0, loc0, Mc);

    // 4) fused: sf/sb GEMMs + gate -> g (bufC)
    gemm_dual<<<dim3(1024 / 128, CH / 128), blk, 0, stream>>>(
        bufA, bufB, pfwb, pbwb, pfb, pbb, xzc, diag, gs, bufC,
        r0, loc0, 1024, 1024);

    // 5) h = x + g @ out_proj^T (fp32) -> hbuf (aliases xzc; xz dead now)
    gemm_bt<2><<<dim3(512 / 128, CH / 128), blk, 0, stream>>>(
        bufC, owb, nullptr, hbuf, x + (size_t)r0 * 512, 512, 1024);

    // 6) LayerNorm -> out rows [r0, r0+CH)   (fp32 store)
    ln_kernel<<<dim3(CH), blk, 0, stream>>>(hbuf, lng, lnb, out, r0);
  }
}

// Round 10
// 616.112 us; speedup vs baseline: 1.1997x; 1.0094x over previous
//
#include <hip/hip_runtime.h>
#include <hip/hip_bf16.h>
#include <cstdint>

// Problem constants
#define T_SEQ  4096
#define DMODEL 512
#define DINNER 1024
#define MTOT   32768            // B*T = 8*4096 rows

typedef __bf16 bf16_t;
typedef bf16_t bf16x8 __attribute__((ext_vector_type(8)));
typedef bf16_t bf16x4v __attribute__((ext_vector_type(4)));
typedef float  f32x4  __attribute__((ext_vector_type(4)));

__device__ __forceinline__ void async_copy16(const bf16_t* g, bf16_t* l) {
  __builtin_amdgcn_global_load_lds(
      (const __attribute__((address_space(1))) void*)g,
      (__attribute__((address_space(3))) void*)l,
      16, 0, 0);
}

__device__ __forceinline__ float silu_f(float v) {
  return v / (1.f + __expf(-v));
}

// T1: bijective XCD-aware block swizzle (m204 form).
__device__ __forceinline__ int xcd_swizzle_flat() {
  const int nwg = gridDim.x * gridDim.y;
  const int orig = blockIdx.y * gridDim.x + blockIdx.x;
  const int q = nwg >> 3, r = nwg & 7;
  const int xcd = orig & 7, lid = orig >> 3;
  return (xcd < r ? xcd * (q + 1) : r * (q + 1) + (xcd - r) * q) + lid;
}

// fp32 -> bf16 cast, 4 elements/thread
__global__ __launch_bounds__(256) void cast_kernel(
    const float* __restrict__ s, bf16_t* __restrict__ d, int n4)
{
  const int i = blockIdx.x * 256 + threadIdx.x;
  if (i < n4) {
    const f32x4 v = ((const f32x4*)s)[i];
    bf16x4v o;
    o[0] = (bf16_t)v[0]; o[1] = (bf16_t)v[1];
    o[2] = (bf16_t)v[2]; o[3] = (bf16_t)v[3];
    ((bf16x4v*)d)[i] = o;
  }
}

// Transpose conv weight (DINNER,1,7) [c][k] -> wt[k][c] (7 x 1024 f32)
__global__ __launch_bounds__(256) void wtr_kernel(
    const float* __restrict__ w, float* __restrict__ wt)
{
  const int i = blockIdx.x * 256 + threadIdx.x;   // 7*1024 = 7168
  if (i < 7 * DINNER) {
    const int c = i & (DINNER - 1);
    const int k = i >> 10;
    wt[i] = w[c * 7 + k];
  }
}

// ---------------------------------------------------------------------------
// T2 LDS XOR-swizzle (rule #21 compliant; R9 PMC: 2.5e7 bank-conflicts =
// ~35% of dual's cycles from 16-way conflicts on ds_read_b128 at 128B row
// stride). Scheme: element (row, slot) of a 128x64-bf16 tile (slot = 16B
// column chunk, 8 per row) is stored at LDS slot (slot ^ (row&7)).
//  - global_load_lds dest stays LINEAR (HW requirement, m104): thread tid
//    owns LDS (row = tid>>3 (+32i), slot = tid&7); it therefore loads the
//    INVERSE-swizzled global column ((tid&7) ^ ((tid>>3)&7))*8 — per-thread
//    constant, and each 8-lane group still covers one contiguous 128B row
//    segment (permuted) so global coalescing is preserved.
//  - ds_read XORs the slot with (lane&7): 16-lane groups hit all 8 slots
//    2x each -> 2-way aliasing = free (m136).
// ---------------------------------------------------------------------------

// MFMA GEMM — 2-phase double-buffer, statically-named LDS buffers (R8
// verified: no hipcc serialization, unlike runtime-indexed sA[cur] in R3)
// + T2 swizzle + T1 XCD swizzle.
// C[m,n] = sum_k A[m,k]*B[n,k]; A: MxK, B: NxK, both row-major bf16.
// EPI 0: plain bf16 store
// EPI 2: +resid(f32), f32 store
// Requires K % 128 == 0.
template <int EPI>
__global__ __launch_bounds__(256, 2) void gemm_bt(
    const bf16_t* __restrict__ A, const bf16_t* __restrict__ B,
    bf16_t* __restrict__ Cb, float* __restrict__ Cf,
    const float* __restrict__ resid,
    int N, int K)
{
  constexpr int BM = 128, BN = 128, BK = 64;
  __shared__ __attribute__((aligned(16))) bf16_t sA0[BM * BK];
  __shared__ __attribute__((aligned(16))) bf16_t sB0[BN * BK];
  __shared__ __attribute__((aligned(16))) bf16_t sA1[BM * BK];
  __shared__ __attribute__((aligned(16))) bf16_t sB1[BN * BK];

  const int tid  = threadIdx.x;
  const int bflat = xcd_swizzle_flat();
  const int m0 = (bflat / gridDim.x) * BM;
  const int n0 = (bflat % gridDim.x) * BN;

  const int w    = tid >> 6, lane = tid & 63;
  const int wm   = (w & 1) << 6, wn = (w >> 1) << 6;   // 2x2 waves -> 64x64 each
  const int quad = lane >> 4, lrow = lane & 15;
  const int l7   = lane & 7;                            // read-side xor key

  // Per-thread staging geometry (constant across K-steps).
  const int f0  = tid << 3;                // flat bf16 index, i=0 slice (LINEAR dest)
  const int sr  = tid >> 3;                // LDS row for i=0 (rows step by 32 per i)
  const int scs = (((tid & 7) ^ (sr & 7)) << 3);  // inverse-swizzled SOURCE col (bf16)

  f32x4 acc[4][4] = {};

  auto STAGE = [&](int kt, bf16_t* dA, bf16_t* dB) {
#pragma unroll
    for (int i = 0; i < 4; ++i) {
      const int f = f0 + (i << 11);        // +i*256*8 bf16
      const int r = sr + (i << 5);         // +i*32 rows ((r&7) invariant in i)
      async_copy16(&A[(size_t)(m0 + r) * K + kt + scs], &dA[f]);
      async_copy16(&B[(size_t)(n0 + r) * K + kt + scs], &dB[f]);
    }
  };

  auto COMPUTE = [&](const bf16_t* cA, const bf16_t* cB) {
#pragma unroll
    for (int ks = 0; ks < 2; ++ks) {
      const int co = (((ks * 4 + quad) ^ l7) << 3);   // swizzled read col (bf16)
      bf16x8 av[4], bv[4];
#pragma unroll
      for (int i = 0; i < 4; ++i) {
        av[i] = *(const bf16x8*)&cA[(wm + i * 16 + lrow) * BK + co];
        bv[i] = *(const bf16x8*)&cB[(wn + i * 16 + lrow) * BK + co];
      }
#pragma unroll
      for (int mi = 0; mi < 4; ++mi)
#pragma unroll
        for (int ni = 0; ni < 4; ++ni)
          acc[mi][ni] = __builtin_amdgcn_mfma_f32_16x16x32_bf16(
              av[mi], bv[ni], acc[mi][ni], 0, 0, 0);
    }
  };

  // Prologue: stage tile 0 into buf0, single drain.
  STAGE(0, sA0, sB0);
  __syncthreads();

  // 2x-unrolled pipeline. Even tile lives in buf0, odd in buf1.
  for (int kt = 0; kt < K; kt += 2 * BK) {
    if (kt + BK < K) STAGE(kt + BK, sA1, sB1);   // prefetch odd tile
    COMPUTE(sA0, sB0);                           // compute even tile (covered)
    __syncthreads();                             // drain buf1 loads; buf0 free
    if (kt + 2 * BK < K) STAGE(kt + 2 * BK, sA0, sB0);
    COMPUTE(sA1, sB1);
    __syncthreads();
  }

  // C/D layout: col = lane&15, row = quad*4 + reg   [m89/m91 verified]
#pragma unroll
  for (int mi = 0; mi < 4; ++mi)
#pragma unroll
    for (int ni = 0; ni < 4; ++ni)
#pragma unroll
      for (int r = 0; r < 4; ++r) {
        const int row = m0 + wm + mi * 16 + (quad << 2) + r;
        const int col = n0 + wn + ni * 16 + lrow;
        float v = acc[mi][ni][r];
        if constexpr (EPI == 0) {
          Cb[(size_t)row * N + col] = (bf16_t)v;
        } else {
          v += resid[(size_t)row * N + col];
          Cf[(size_t)row * N + col] = v;
        }
      }
}

// Fused dual GEMM + gate (steps 3+5+6), 2-phase pipelined (R9: +7 us) +
// T2 swizzle (this round):
//   sf = silu(A1 @ B1^T + b1)   (in registers, never touches HBM)
//   sb = silu(A2 @ B2^T + b2)   (in registers)
//   G  = (sf*[t>0] + sb*[t<T-1] + xp*diag) * silu(z) * gs
// Per K-step: {stage bwd[kt] ; compute fwd[kt] ; bar ; stage fwd[kt+1] ;
// compute bwd[kt] ; bar} — every drain covered by a 32-MFMA phase, LDS
// stays 64 KiB (2 blocks/CU). Statically-named buffers (R8 discipline).
__global__ __launch_bounds__(256, 2) void gemm_dual(
    const bf16_t* __restrict__ A1, const bf16_t* __restrict__ A2,
    const bf16_t* __restrict__ B1, const bf16_t* __restrict__ B2,
    const float* __restrict__ b1, const float* __restrict__ b2,
    const bf16_t* __restrict__ xzc, const float* __restrict__ diag,
    const float* __restrict__ gs, bf16_t* __restrict__ G,
    int r0, int loc0, int N, int K)
{
  constexpr int BM = 128, BN = 128, BK = 64;
  __shared__ __attribute__((aligned(16))) bf16_t sA1l[BM * BK];
  __shared__ __attribute__((aligned(16))) bf16_t sA2l[BM * BK];
  __shared__ __attribute__((aligned(16))) bf16_t sB1l[BN * BK];
  __shared__ __attribute__((aligned(16))) bf16_t sB2l[BN * BK];

  const int tid  = threadIdx.x;
  const int bflat = xcd_swizzle_flat();
  const int m0 = (bflat / gridDim.x) * BM;
  const int n0 = (bflat % gridDim.x) * BN;

  const int w    = tid >> 6, lane = tid & 63;
  const int wm   = (w & 1) << 6, wn = (w >> 1) << 6;
  const int quad = lane >> 4, lrow = lane & 15;
  const int l7   = lane & 7;

  const int f0  = tid << 3;
  const int sr  = tid >> 3;
  const int scs = (((tid & 7) ^ (sr & 7)) << 3);

  f32x4 accf[4][4] = {};
  f32x4 accb[4][4] = {};

  // Stage one operand pair (gA -> dA, gB -> dB) for K-offset kt.
  auto STAGE = [&](int kt, const bf16_t* gA, const bf16_t* gB,
                   bf16_t* dA, bf16_t* dB) {
#pragma unroll
    for (int i = 0; i < 4; ++i) {
      const int f = f0 + (i << 11);
      const int r = sr + (i << 5);
      async_copy16(&gA[(size_t)(m0 + r) * K + kt + scs], &dA[f]);
      async_copy16(&gB[(size_t)(n0 + r) * K + kt + scs], &dB[f]);
    }
  };

  auto COMPUTE = [&](const bf16_t* cA, const bf16_t* cB, f32x4 (*acc)[4]) {
#pragma unroll
    for (int ks = 0; ks < 2; ++ks) {
      const int co = (((ks * 4 + quad) ^ l7) << 3);
      bf16x8 av[4], bv[4];
#pragma unroll
      for (int i = 0; i < 4; ++i) {
        av[i] = *(const bf16x8*)&cA[(wm + i * 16 + lrow) * BK + co];
        bv[i] = *(const bf16x8*)&cB[(wn + i * 16 + lrow) * BK + co];
      }
#pragma unroll
      for (int mi = 0; mi < 4; ++mi)
#pragma unroll
        for (int ni = 0; ni < 4; ++ni)
          acc[mi][ni] = __builtin_amdgcn_mfma_f32_16x16x32_bf16(
              av[mi], bv[ni], acc[mi][ni], 0, 0, 0);
    }
  };

  // Prologue: stage fwd operands of tile 0; drain.
  STAGE(0, A1, B1, sA1l, sB1l);
  __syncthreads();

  for (int kt = 0; kt < K; kt += BK) {
    STAGE(kt, A2, B2, sA2l, sB2l);            // issue bwd[kt] loads
    COMPUTE(sA1l, sB1l, accf);                // fwd[kt] covers them
    __syncthreads();                          // bwd[kt] ready; sA1l/sB1l free
    if (kt + BK < K) STAGE(kt + BK, A1, B1, sA1l, sB1l);  // issue fwd[kt+1]
    COMPUTE(sA2l, sB2l, accb);                // bwd[kt] covers them
    __syncthreads();                          // fwd[kt+1] ready; sA2l/sB2l free
  }

  // Epilogue: per-element gate, all in registers.
  const float gsv = gs[0];
  int   colv[4];
  float b1v[4], b2v[4], dgv[4];
#pragma unroll
  for (int ni = 0; ni < 4; ++ni) {
    const int col = n0 + wn + ni * 16 + lrow;
    colv[ni] = col;
    b1v[ni] = b1[col];
    b2v[ni] = b2[col];
    dgv[ni] = diag[col];
  }
#pragma unroll
  for (int mi = 0; mi < 4; ++mi)
#pragma unroll
    for (int r = 0; r < 4; ++r) {
      const int row = m0 + wm + mi * 16 + (quad << 2) + r;
      const int t = (row + r0) & (T_SEQ - 1);
      const bool tf = (t > 0), tb = (t < T_SEQ - 1);
      const bf16_t* xrow = &xzc[(size_t)(loc0 + row) * 2048];
#pragma unroll
      for (int ni = 0; ni < 4; ++ni) {
        const float sf = silu_f(accf[mi][ni][r] + b1v[ni]);
        const float sb = silu_f(accb[mi][ni][r] + b2v[ni]);
        const float xp = (float)xrow[colv[ni]];
        const float z  = (float)xrow[colv[ni] + DINNER];
        float y = xp * dgv[ni];
        if (tf) y += sf;
        if (tb) y += sb;
        G[(size_t)row * N + colv[ni]] = (bf16_t)(y * silu_f(z) * gsv);
      }
    }
}

// Depthwise causal conv, one direction, shift_right folded in.
// Register-blocked + vectorized: each thread = 4 consecutive t x 8 channels.
template <int DIR>
__global__ __launch_bounds__(256) void conv_kernel(
    const bf16_t* __restrict__ xzc,
    const float* __restrict__ wt, const float* __restrict__ bc,
    bf16_t* __restrict__ vout, int r0, int loc0, int Mc)
{
  const int idx = blockIdx.x * 256 + threadIdx.x;   // over CH*DINNER/32
  const int c8  = idx & 127;                        // 8-channel group
  const int tg  = idx >> 7;                         // 4-row time group
  const int bt0 = tg << 2;                          // chunk-local first row
  const int t0  = (bt0 + r0) & (T_SEQ - 1);         // in-sequence t of first row
  const int lt0 = bt0 + loc0;                       // local row in xzc
  const int cc  = c8 << 3;

  float wv[7][8];
#pragma unroll
  for (int k = 0; k < 7; ++k) {
    const f32x4 a = *(const f32x4*)&wt[k * DINNER + cc];
    const f32x4 b = *(const f32x4*)&wt[k * DINNER + cc + 4];
#pragma unroll
    for (int u = 0; u < 4; ++u) { wv[k][u] = a[u]; wv[k][u + 4] = b[u]; }
  }

  float acc[4][8];
  {
    const f32x4 a = *(const f32x4*)&bc[cc];
    const f32x4 b = *(const f32x4*)&bc[cc + 4];
#pragma unroll
    for (int i = 0; i < 4; ++i)
#pragma unroll
      for (int u = 0; u < 4; ++u) { acc[i][u] = a[u]; acc[i][u + 4] = b[u]; }
  }

#pragma unroll
  for (int rr = 0; rr < 10; ++rr) {
    int lt = (DIR == 0) ? (lt0 - 7 + rr) : (lt0 + 1 + rr);
    lt = lt < 0 ? 0 : (lt > Mc - 1 ? Mc - 1 : lt);
    const bf16x8 xv = *(const bf16x8*)&xzc[(size_t)lt * 2048 + cc];
    float xf[8];
#pragma unroll
    for (int u = 0; u < 8; ++u) xf[u] = (float)xv[u];
#pragma unroll
    for (int i = 0; i < 4; ++i) {
      const int k = (DIR == 0) ? (rr - i) : (i + 6 - rr);
      if (k >= 0 && k <= 6) {
        const bool ok = (DIR == 0) ? (t0 + i >= 7 - k)
                                   : (t0 + i <= (T_SEQ - 8) + k);
        if (ok) {
#pragma unroll
          for (int u = 0; u < 8; ++u) acc[i][u] += wv[k][u] * xf[u];
        }
      }
    }
  }

#pragma unroll
  for (int i = 0; i < 4; ++i) {
    bf16x8 o;
#pragma unroll
    for (int u = 0; u < 8; ++u) o[u] = (bf16_t)acc[i][u];
    *(bf16x8*)&vout[(size_t)(bt0 + i) * DINNER + cc] = o;
  }
}

// LayerNorm over D=512, one block (256 threads) per chunk-local row.
__global__ __launch_bounds__(256) void ln_kernel(
    const float* __restrict__ h,
    const float* __restrict__ lng, const float* __restrict__ lnb,
    float* __restrict__ out, int r0)
{
  const int row = blockIdx.x;                        // local row
  const int tid = threadIdx.x;
  const float* hr = h + (size_t)row * DMODEL;
  const float v0 = hr[tid], v1 = hr[tid + 256];
  float s  = v0 + v1;
  float ss = v0 * v0 + v1 * v1;
#pragma unroll
  for (int off = 1; off < 64; off <<= 1) {
    s  += __shfl_xor(s, off);
    ss += __shfl_xor(ss, off);
  }
  __shared__ float ps[8];
  const int w = tid >> 6;
  if ((tid & 63) == 0) { ps[w] = s; ps[w + 4] = ss; }
  __syncthreads();
  s  = ps[0] + ps[1] + ps[2] + ps[3];
  ss = ps[4] + ps[5] + ps[6] + ps[7];
  const float mu  = s * (1.f / DMODEL);
  const float inv = rsqrtf(ss * (1.f / DMODEL) - mu * mu + 1e-5f);
  float* o = out + (size_t)(r0 + row) * DMODEL;
  o[tid]       = (v0 - mu) * inv * lng[tid]       + lnb[tid];
  o[tid + 256] = (v1 - mu) * inv * lng[tid + 256] + lnb[tid + 256];
}

extern "C" void kernel_launch(void* const* d_in, const int* in_sizes, int n_in,
                              void* d_out, int out_size, void* d_ws, size_t ws_size,
                              hipStream_t stream) {
  const float* x    = (const float*)d_in[0];
  const float* in_w = (const float*)d_in[1];
  const float* cfw  = (const float*)d_in[2];
  const float* cfb  = (const float*)d_in[3];
  const float* pfw  = (const float*)d_in[4];
  const float* pfb  = (const float*)d_in[5];
  const float* cbw  = (const float*)d_in[6];
  const float* cbb  = (const float*)d_in[7];
  const float* pbw  = (const float*)d_in[8];
  const float* pbb  = (const float*)d_in[9];
  const float* diag = (const float*)d_in[10];
  const float* gs   = (const float*)d_in[11];
  const float* ow   = (const float*)d_in[12];
  const float* lng  = (const float*)d_in[13];
  const float* lnb  = (const float*)d_in[14];
  float* out = (float*)d_out;

  char* ws = (char*)d_ws;

  // Persistent bf16 copies of GEMM operand tensors + transposed conv weights:
  bf16_t* xw   = (bf16_t*)(ws);                         // 32768x512   (32 MiB)
  bf16_t* inwb = (bf16_t*)(ws + (size_t)33554432);      // 2048x512    (2 MiB)
  bf16_t* pfwb = (bf16_t*)(ws + (size_t)35651584);      // 1024x1024   (2 MiB)
  bf16_t* pbwb = (bf16_t*)(ws + (size_t)37748736);      // 1024x1024   (2 MiB)
  bf16_t* owb  = (bf16_t*)(ws + (size_t)39845888);      // 512x1024    (1 MiB)
  float*  wtf  = (float*)(ws + (size_t)40894464);       // 7x1024 f32  (28 KiB)
  float*  wtb  = (float*)(ws + (size_t)40923136);       // 7x1024 f32  (28 KiB)
  const size_t persist = 40951808;

  // Workspace-adaptive chunking. (Observed: CH=16384 fits -> 2 chunks.)
  // req(CH) = persist + (CH+256)*4096 + 3*CH*2048 bytes
  int CH = 128;
  {
    const int cands[9] = {32768, 16384, 8192, 4096, 2048, 1024, 512, 256, 128};
    for (int i = 0; i < 9; ++i) {
      const size_t req = persist + (size_t)(cands[i] + 256) * 4096 +
                         (size_t)3 * cands[i] * 2048;
      if (ws_size >= req) { CH = cands[i]; break; }
    }
  }

  char* cb = ws + persist;
  const size_t xz_cap = (size_t)(CH + 256) * 4096;      // bytes
  bf16_t* xzc  = (bf16_t*)cb;
  bf16_t* bufA = (bf16_t*)(cb + xz_cap);                      // v_fwd
  bf16_t* bufB = (bf16_t*)(cb + xz_cap + (size_t)CH * 2048);  // v_bwd
  bf16_t* bufC = (bf16_t*)(cb + xz_cap + (size_t)CH * 4096);  // g
  float*  hbuf = (float*)cb;                             // aliases xzc (dead by then)

  dim3 blk(256);

  // 0) one-time fp32 -> bf16 casts of GEMM operands + conv-weight transposes
  cast_kernel<<<dim3(16384), blk, 0, stream>>>(x,    xw,   4194304);
  cast_kernel<<<dim3(1024),  blk, 0, stream>>>(in_w, inwb, 262144);
  cast_kernel<<<dim3(1024),  blk, 0, stream>>>(pfw,  pfwb, 262144);
  cast_kernel<<<dim3(1024),  blk, 0, stream>>>(pbw,  pbwb, 262144);
  cast_kernel<<<dim3(512),   blk, 0, stream>>>(ow,   owb,  131072);
  wtr_kernel<<<dim3(28), blk, 0, stream>>>(cfw, wtf);
  wtr_kernel<<<dim3(28), blk, 0, stream>>>(cbw, wtb);

  for (int r0 = 0; r0 < MTOT; r0 += CH) {
    const int g0 = (r0 >= 128) ? (r0 - 128) : 0;
    int g1 = r0 + CH + 128; if (g1 > MTOT) g1 = MTOT;
    const int Mc   = g1 - g0;        // multiple of 128
    const int loc0 = r0 - g0;        // chunk start's local row in xzc

    // 1) xzc = x[g0:g1] @ in_proj_w^T        (Mc x 2048, K=512)
    gemm_bt<0><<<dim3(2048 / 128, Mc / 128), blk, 0, stream>>>(
        xw + (size_t)g0 * 512, inwb, xzc, nullptr, nullptr, 2048, 512);

    // 2) forward shifted causal conv -> v_fwd (bufA)
    conv_kernel<0><<<dim3(CH / 8), blk, 0, stream>>>(
        xzc, wtf, cfb, bufA, r0, loc0, Mc);

    // 3) backward shifted causal conv -> v_bwd (bufB)
    conv_kernel<1><<<dim3(CH / 8), blk, 0, stream>>>(
        xzc, wtb, cbb, bufB, r0, loc0, Mc);

    // 4) fused: sf/sb GEMMs + gate -> g (bufC)
    gemm_dual<<<dim3(1024 / 128, CH / 128), blk, 0, stream>>>(
        bufA, bufB, pfwb, pbwb, pfb, pbb, xzc, diag, gs, bufC,
        r0, loc0, 1024, 1024);

    // 5) h = x + g @ out_proj^T (fp32) -> hbuf (aliases xzc; xz dead now)
    gemm_bt<2><<<dim3(512 / 128, CH / 128), blk, 0, stream>>>(
        bufC, owb, nullptr, hbuf, x + (size_t)r0 * 512, 512, 1024);

    // 6) LayerNorm -> out rows [r0, r0+CH)   (fp32 store)
    ln_kernel<<<dim3(CH), blk, 0, stream>>>(hbuf, lng, lnb, out, r0);
  }
}